// Round 1
// baseline (1573.064 us; speedup 1.0000x reference)
//
#include <hip/hip_runtime.h>
#include <hip/hip_bf16.h>
#include <math.h>

#define B_    16
#define N_    1000
#define BN_   16000
#define T_    16
#define FO    16
#define H_    128
#define G3    384       // 3*H
#define HEADS 5
#define HC    640       // heads*H
#define E_    4000
#define EG    64000     // B*E
#define ETOT  80000     // EG + BN self loops
#define P_    8
#define A_    8
#define CHUNKS 2
#define CN    8000      // nodes per chunk
#define NEG_SLOPE 0.2f

__device__ __forceinline__ float fsigmoid(float x){ return 1.0f/(1.0f + __expf(-x)); }
__device__ __forceinline__ float ftanh_(float x){ return 2.0f/(1.0f + __expf(-2.0f*x)) - 1.0f; }
__device__ __forceinline__ float bf2f(unsigned short u){ return __uint_as_float(((unsigned)u)<<16); }
__device__ __forceinline__ void f4a(float4 v, float* a){ a[0]=v.x; a[1]=v.y; a[2]=v.z; a[3]=v.w; }

// ---------------- K0: transpose W_ih, W_hh (384x128 -> 128x384) ----------------
__global__ void k_transpose(const float* __restrict__ Wih, const float* __restrict__ Whh,
                            float* __restrict__ WihT, float* __restrict__ WhhT){
    int i = blockIdx.x*256 + threadIdx.x;
    if(i < G3*H_){
        int j = i / H_, k = i - j*H_;
        WihT[k*G3 + j] = Wih[i];
        WhhT[k*G3 + j] = Whh[i];
    }
}

// ---------------- K_init: zero/seed atomics buffers ----------------
__global__ void k_init(unsigned* __restrict__ segmax, float* __restrict__ segsum,
                       float* __restrict__ node_out, float* __restrict__ tacc){
    int i = blockIdx.x*256 + threadIdx.x;
    if(i < BN_*HEADS){ segmax[i] = 0x007FFFFFu; segsum[i] = 0.0f; } // encode(-inf)
    if(i < B_*HC)  node_out[i] = 0.0f;
    if(i < B_*H_)  tacc[i] = 0.0f;
}

// ---------------- K1: fused obs-MLP + gx = relu(obs@Wn+bn)@WihT + bih (bf16 out) --------
// block: 32 rows x 384 cols, 256 threads. rows are (node,t) pairs, chunk-local.
__global__ __launch_bounds__(256) void k_gx(const float* __restrict__ obs,
        const float* __restrict__ Wn, const float* __restrict__ bn,
        const float* __restrict__ WihT, const float* __restrict__ bih,
        __hip_bfloat16* __restrict__ gx, int chunk_row_base){
    __shared__ float sObs[32][17];
    __shared__ float sWn[FO*H_];
    __shared__ float sX[32][132];
    int t = threadIdx.x;
    int rowBase = chunk_row_base + blockIdx.x*32;     // global obs row
    for(int i = t; i < 32*16; i += 256)
        sObs[i>>4][i&15] = obs[(size_t)(rowBase + (i>>4))*FO + (i&15)];
    for(int i = t; i < FO*H_; i += 256) sWn[i] = Wn[i];
    __syncthreads();
    { // x = relu(obs @ Wn + bn): thread: row r=t&31, 16 cols
        int r = t & 31, c0 = (t>>5)*16;
        float acc[16];
        #pragma unroll
        for(int i=0;i<16;i++) acc[i] = bn[c0+i];
        #pragma unroll
        for(int f=0; f<FO; f++){
            float ov = sObs[r][f];
            #pragma unroll
            for(int i=0;i<16;i++) acc[i] = fmaf(ov, sWn[f*H_ + c0 + i], acc[i]);
        }
        #pragma unroll
        for(int i=0;i<16;i++) sX[r][c0+i] = fmaxf(acc[i], 0.0f);
    }
    __syncthreads();
    // GEMM 32x384, K=128; thread: 4 rows x 12 cols
    int rg = t & 7, cg = t >> 3;
    int r0 = rg*4, j0 = cg*12;
    float acc[4][12];
    #pragma unroll
    for(int i=0;i<4;i++){
        #pragma unroll
        for(int j=0;j<12;j++) acc[i][j]=0.f;
    }
    for(int k=0;k<H_;k+=4){
        float xv[4][4];
        #pragma unroll
        for(int i=0;i<4;i++) f4a(*(const float4*)&sX[r0+i][k], xv[i]);
        #pragma unroll
        for(int kk=0;kk<4;kk++){
            const float* wrow = &WihT[(size_t)(k+kk)*G3 + j0];
            float wv[12];
            f4a(*(const float4*)(wrow),   wv);
            f4a(*(const float4*)(wrow+4), wv+4);
            f4a(*(const float4*)(wrow+8), wv+8);
            #pragma unroll
            for(int i=0;i<4;i++){
                float xs = xv[i][kk];
                #pragma unroll
                for(int j=0;j<12;j++) acc[i][j] = fmaf(xs, wv[j], acc[i][j]);
            }
        }
    }
    int lrow0 = blockIdx.x*32 + r0;                   // chunk-local gx row
    #pragma unroll
    for(int i=0;i<4;i++){
        __hip_bfloat16* gp = &gx[(size_t)(lrow0+i)*G3 + j0];
        #pragma unroll
        for(int j=0;j<12;j++) gp[j] = __float2bfloat16(acc[i][j] + bih[j0+j]);
    }
}

// ---------------- K2: GRU recurrence, 16 nodes/block, h in LDS ----------------
__global__ __launch_bounds__(256) void k_gru(const __hip_bfloat16* __restrict__ gx,
        const float* __restrict__ WhhT, const float* __restrict__ bhh,
        float* __restrict__ hout, int chunk_node_base){
    __shared__ float sH[16][132];
    __shared__ float sGh[16][388];
    __shared__ float sBhh[G3];
    int t = threadIdx.x;
    for(int i=t;i<G3;i+=256) sBhh[i] = bhh[i];
    for(int i=t;i<16*132;i+=256) ((float*)sH)[i] = 0.f;
    __syncthreads();
    int n0 = (t & 7)*2, j0 = (t >> 3)*12;   // GEMM map: 2 nodes x 12 cols
    int en = t >> 4, ed0 = (t & 15)*8;      // elementwise map: node en, 8 dims
    int baseLocalNode = blockIdx.x*16;
    for(int step=0; step<T_; step++){
        float acc[2][12];
        #pragma unroll
        for(int i=0;i<2;i++){
            #pragma unroll
            for(int j=0;j<12;j++) acc[i][j]=0.f;
        }
        for(int k=0;k<H_;k+=4){
            float ha[2][4];
            #pragma unroll
            for(int i=0;i<2;i++) f4a(*(const float4*)&sH[n0+i][k], ha[i]);
            #pragma unroll
            for(int kk=0;kk<4;kk++){
                const float* wrow = &WhhT[(size_t)(k+kk)*G3 + j0];
                float wv[12];
                f4a(*(const float4*)(wrow),   wv);
                f4a(*(const float4*)(wrow+4), wv+4);
                f4a(*(const float4*)(wrow+8), wv+8);
                #pragma unroll
                for(int i=0;i<2;i++){
                    float hv = ha[i][kk];
                    #pragma unroll
                    for(int j=0;j<12;j++) acc[i][j] = fmaf(hv, wv[j], acc[i][j]);
                }
            }
        }
        #pragma unroll
        for(int i=0;i<2;i++){
            #pragma unroll
            for(int j=0;j<12;j++) sGh[n0+i][j0+j] = acc[i][j];
        }
        __syncthreads();
        { // gates for 8 dims of node en
            const unsigned short* gxrow =
                (const unsigned short*)&gx[((size_t)(baseLocalNode+en)*T_ + step)*G3];
            ushort4 u0 = *(const ushort4*)(gxrow + ed0);
            ushort4 u1 = *(const ushort4*)(gxrow + ed0 + 4);
            ushort4 v0 = *(const ushort4*)(gxrow + 128 + ed0);
            ushort4 v1 = *(const ushort4*)(gxrow + 128 + ed0 + 4);
            ushort4 w0 = *(const ushort4*)(gxrow + 256 + ed0);
            ushort4 w1 = *(const ushort4*)(gxrow + 256 + ed0 + 4);
            unsigned short gr[8] = {u0.x,u0.y,u0.z,u0.w,u1.x,u1.y,u1.z,u1.w};
            unsigned short gz[8] = {v0.x,v0.y,v0.z,v0.w,v1.x,v1.y,v1.z,v1.w};
            unsigned short gn[8] = {w0.x,w0.y,w0.z,w0.w,w1.x,w1.y,w1.z,w1.w};
            #pragma unroll
            for(int q=0;q<8;q++){
                int d = ed0+q;
                float ghr = sGh[en][d]     + sBhh[d];
                float ghz = sGh[en][d+128] + sBhh[d+128];
                float ghn = sGh[en][d+256] + sBhh[d+256];
                float r  = fsigmoid(bf2f(gr[q]) + ghr);
                float z  = fsigmoid(bf2f(gz[q]) + ghz);
                float nn = ftanh_(bf2f(gn[q]) + r*ghn);
                float hp = sH[en][d];
                sH[en][d] = (1.f - z)*nn + z*hp;
            }
        }
        __syncthreads();
    }
    float* hp = &hout[(size_t)(chunk_node_base + baseLocalNode + en)*H_ + ed0];
    #pragma unroll
    for(int q=0;q<8;q++) hp[q] = sH[en][ed0+q];
}

// ---------------- K3: xl = h@Wl, xr = h@Wr  (M=16000, N=2x640, K=128) ----------------
__global__ __launch_bounds__(256) void k_xlxr(const float* __restrict__ h,
        const float* __restrict__ Wl, const float* __restrict__ Wr,
        float* __restrict__ xl, float* __restrict__ xr){
    __shared__ float sH[64][132];
    int t = threadIdx.x;
    int r0 = blockIdx.x*64;
    int cblk = blockIdx.y*64;      // 0..1279 over [Wl|Wr]
    for(int i=t; i<64*32; i+=256){
        int row = i >> 5, kq = (i & 31)*4;
        *(float4*)&sH[row][kq] = *(const float4*)&h[(size_t)(r0+row)*H_ + kq];
    }
    __syncthreads();
    int rr = (t & 15)*4, cc = cblk + (t >> 4)*4;
    const float* W; float* Out; int cw;
    if(cc < HC){ W = Wl; Out = xl; cw = cc; } else { W = Wr; Out = xr; cw = cc - HC; }
    float acc[4][4];
    #pragma unroll
    for(int i=0;i<4;i++){
        #pragma unroll
        for(int j=0;j<4;j++) acc[i][j]=0.f;
    }
    for(int k=0;k<H_;k+=4){
        float ha[4][4];
        #pragma unroll
        for(int i=0;i<4;i++) f4a(*(const float4*)&sH[rr+i][k], ha[i]);
        #pragma unroll
        for(int kk=0;kk<4;kk++){
            float4 w = *(const float4*)&W[(size_t)(k+kk)*HC + cw];
            #pragma unroll
            for(int i=0;i<4;i++){
                float hv = ha[i][kk];
                acc[i][0]=fmaf(hv,w.x,acc[i][0]); acc[i][1]=fmaf(hv,w.y,acc[i][1]);
                acc[i][2]=fmaf(hv,w.z,acc[i][2]); acc[i][3]=fmaf(hv,w.w,acc[i][3]);
            }
        }
    }
    #pragma unroll
    for(int i=0;i<4;i++)
        *(float4*)&Out[(size_t)(r0+rr+i)*HC + cw] =
            make_float4(acc[i][0],acc[i][1],acc[i][2],acc[i][3]);
}

// ---------------- edge src/dst helper ----------------
__device__ __forceinline__ void edge_sd(int e, const int* __restrict__ edges, int* src, int* dst){
    if(e < EG){
        int b = e / E_, j = e - b*E_;
        *src = edges[(b*2+0)*E_ + j] + b*N_;
        *dst = edges[(b*2+1)*E_ + j] + b*N_;
    } else { *src = *dst = e - EG; }
}

// ---------------- K4: GATv2 edge logits (one wave per edge) ----------------
__global__ __launch_bounds__(256) void k_logits(const float* __restrict__ xl,
        const float* __restrict__ xr, const int* __restrict__ edges,
        const float* __restrict__ atta, float* __restrict__ logits){
    __shared__ float sA[HEADS*H_];
    int t = threadIdx.x;
    for(int i=t;i<HEADS*H_;i+=256) sA[i]=atta[i];
    __syncthreads();
    int lane = t & 63;
    int e = blockIdx.x*4 + (t >> 6);
    if(e >= ETOT) return;
    int src, dst; edge_sd(e, edges, &src, &dst);
    const float* xls = &xl[(size_t)src*HC];
    const float* xrd = &xr[(size_t)dst*HC];
    for(int hh=0; hh<HEADS; hh++){
        float s1 = xls[hh*H_+lane]    + xrd[hh*H_+lane];
        float s2 = xls[hh*H_+lane+64] + xrd[hh*H_+lane+64];
        s1 = s1 > 0.f ? s1 : NEG_SLOPE*s1;
        s2 = s2 > 0.f ? s2 : NEG_SLOPE*s2;
        float p = s1*sA[hh*H_+lane] + s2*sA[hh*H_+lane+64];
        #pragma unroll
        for(int off=32; off; off>>=1) p += __shfl_xor(p, off);
        if(lane==0) logits[(size_t)e*HEADS+hh] = p;
    }
}

// ---------------- K5a: segment max (monotone-uint float encoding) ----------------
__global__ void k_segmax(const float* __restrict__ logits, const int* __restrict__ edges,
                         unsigned* __restrict__ segmax){
    int idx = blockIdx.x*256 + threadIdx.x;
    if(idx >= ETOT*HEADS) return;
    int e = idx / HEADS, hh = idx - e*HEADS;
    int src, dst; edge_sd(e, edges, &src, &dst);
    unsigned u = __float_as_uint(logits[idx]);
    u = (u & 0x80000000u) ? ~u : (u | 0x80000000u);
    atomicMax(&segmax[dst*HEADS+hh], u);
}

// ---------------- K5b: p = exp(logit - m), segsum += p ----------------
__global__ void k_expsum(float* __restrict__ pbuf, const int* __restrict__ edges,
                         const unsigned* __restrict__ segmax, float* __restrict__ segsum){
    int idx = blockIdx.x*256 + threadIdx.x;
    if(idx >= ETOT*HEADS) return;
    int e = idx / HEADS, hh = idx - e*HEADS;
    int src, dst; edge_sd(e, edges, &src, &dst);
    unsigned u = segmax[dst*HEADS+hh];
    float m = (u & 0x80000000u) ? __uint_as_float(u ^ 0x80000000u) : __uint_as_float(~u);
    float p = __expf(pbuf[idx] - m);
    pbuf[idx] = p;
    atomicAdd(&segsum[dst*HEADS+hh], p);
}

// ---------------- K5c: alpha out + sparse node_out accumulation ----------------
__global__ void k_alpha(const float* __restrict__ pbuf, const float* __restrict__ segsum,
                        const int* __restrict__ edges, const float* __restrict__ xl,
                        float* __restrict__ out_alpha, float* __restrict__ node_out){
    int idx = blockIdx.x*256 + threadIdx.x;
    if(idx >= ETOT*HEADS) return;
    int e = idx / HEADS, hh = idx - e*HEADS;
    int src, dst; edge_sd(e, edges, &src, &dst);
    float a = pbuf[idx] / segsum[dst*HEADS+hh];
    out_alpha[idx] = a;
    if(dst % N_ == 0){   // only ego nodes b*N feed the head
        int b = dst / N_;
        const float* x = &xl[(size_t)src*HC + hh*H_];
        float* no = &node_out[b*HC + hh*H_];
        for(int c=0;c<H_;c++) atomicAdd(&no[c], a * x[c]);
    }
}

// ---------------- K6: conv1 4->32, 32x32 -> 16x16, stride2 SAME(pad lo 0, hi 1) -------
__global__ __launch_bounds__(256) void k_conv1(const float* __restrict__ im,
        const float* __restrict__ w, const float* __restrict__ bias, float* __restrict__ outp){
    __shared__ float sW[32*4*9];
    int t = threadIdx.x;
    for(int i=t;i<32*4*9;i+=256) sW[i]=w[i];
    __syncthreads();
    int idx = blockIdx.x*256 + t;
    if(idx >= 16*32*16*16) return;
    int ox = idx & 15, oy = (idx>>4)&15, oc = (idx>>8)&31, b = idx>>13;
    float acc = bias[oc];
    for(int ic=0;ic<4;ic++){
        const float* ip = &im[(size_t)((b*4+ic)*32)*32];
        const float* wp = &sW[(oc*4+ic)*9];
        #pragma unroll
        for(int ky=0;ky<3;ky++){
            int iy = oy*2+ky; if(iy>=32) continue;
            #pragma unroll
            for(int kx=0;kx<3;kx++){
                int ix = ox*2+kx; if(ix>=32) continue;
                acc = fmaf(ip[iy*32+ix], wp[ky*3+kx], acc);
            }
        }
    }
    outp[idx] = fmaxf(acc, 0.f);
}

// ---------------- K7: conv2 32->64, 16x16 -> 8x8 ----------------
__global__ __launch_bounds__(256) void k_conv2(const float* __restrict__ c1,
        const float* __restrict__ w, const float* __restrict__ bias, float* __restrict__ outp){
    int idx = blockIdx.x*256 + threadIdx.x;
    if(idx >= 16*64*8*8) return;
    int ox = idx & 7, oy = (idx>>3)&7, oc = (idx>>6)&63, b = idx>>12;
    float acc = bias[oc];
    for(int ic=0;ic<32;ic++){
        const float* ip = &c1[(size_t)((b*32+ic)*16)*16];
        const float* wp = &w[(oc*32+ic)*9];
        #pragma unroll
        for(int ky=0;ky<3;ky++){
            int iy = oy*2+ky; if(iy>=16) continue;
            #pragma unroll
            for(int kx=0;kx<3;kx++){
                int ix = ox*2+kx; if(ix>=16) continue;
                acc = fmaf(ip[iy*16+ix], wp[ky*3+kx], acc);
            }
        }
    }
    outp[idx] = fmaxf(acc, 0.f);
}

// ---------------- K8: temb partial GEMM [16,4096]@[4096,128] via k-split atomics ------
__global__ void k_tembacc(const float* __restrict__ c2, const float* __restrict__ Wc,
                          float* __restrict__ tacc){
    int t = threadIdx.x;
    int b = blockIdx.x >> 3, ks = blockIdx.x & 7;
    int j = t & 127, sub = t >> 7;
    int k0 = ks*512 + sub*256;
    const float* cp = &c2[(size_t)b*4096];
    float acc = 0.f;
    for(int k=k0;k<k0+256;k++) acc = fmaf(cp[k], Wc[(size_t)k*H_+j], acc);
    atomicAdd(&tacc[b*H_+j], acc);
}

// ---------------- K9: head (obs_gat mean + temb + phase MLP + fusion + dueling) -------
__global__ __launch_bounds__(256) void k_head(const float* __restrict__ node_out,
        const float* __restrict__ gat_bias, const float* __restrict__ tacc,
        const float* __restrict__ bc, const float* __restrict__ phase,
        const float* __restrict__ Wp, const float* __restrict__ bp,
        const float* __restrict__ Wh, const float* __restrict__ bh,
        const float* __restrict__ Wo, const float* __restrict__ bo,
        const float* __restrict__ Wa, const float* __restrict__ ba,
        float* __restrict__ out){
    __shared__ float sF[16][268];
    __shared__ float sHid[16][132];
    int t = threadIdx.x;
    for(int i=t;i<B_*H_;i+=256){
        int b=i>>7, c=i&127;
        float s=0.f;
        #pragma unroll
        for(int hh=0;hh<HEADS;hh++) s += node_out[b*HC + hh*H_ + c];
        sF[b][c] = s*(1.0f/HEADS) + gat_bias[c];
    }
    for(int i=t;i<B_*H_;i+=256){
        int b=i>>7, c=i&127;
        sF[b][128+c] = fmaxf(tacc[i] + bc[c], 0.f);
    }
    if(t < B_*P_){
        int b=t>>3, p=t&7;
        float s=bp[p];
        #pragma unroll
        for(int q=0;q<P_;q++) s = fmaf(phase[b*P_+q], Wp[q*P_+p], s);
        sF[b][256+p] = fmaxf(s, 0.f);
    }
    __syncthreads();
    for(int i=t;i<B_*H_;i+=256){
        int b=i>>7, j=i&127;
        float s=bh[j];
        for(int k=0;k<2*H_+P_;k++) s = fmaf(sF[b][k], Wh[k*H_+j], s);
        sHid[b][j]=fmaxf(s,0.f);
    }
    __syncthreads();
    if(t < B_*A_){
        int b=t>>3, a=t&7;
        float v=bo[0], ad=ba[a];
        for(int k=0;k<H_;k++){ float hv=sHid[b][k]; v = fmaf(hv,Wo[k],v); ad = fmaf(hv,Wa[k*A_+a],ad); }
        float m = ad;
        m += __shfl_xor(m,1); m += __shfl_xor(m,2); m += __shfl_xor(m,4);
        m *= 0.125f;
        out[b*A_+a] = v + ad - m;
    }
}

extern "C" void kernel_launch(void* const* d_in, const int* in_sizes, int n_in,
                              void* d_out, int out_size, void* d_ws, size_t ws_size,
                              hipStream_t stream) {
    (void)in_sizes; (void)n_in; (void)out_size; (void)ws_size;
    const float* obs      = (const float*)d_in[0];
    const float* phase    = (const float*)d_in[1];
    const float* obs_map  = (const float*)d_in[2];
    const int*   edges    = (const int*)  d_in[3];
    // d_in[4] edges_feature: unused by reference
    const float* W_nbrs   = (const float*)d_in[5];
    const float* b_nbrs   = (const float*)d_in[6];
    const float* W_ih     = (const float*)d_in[7];
    const float* W_hh     = (const float*)d_in[8];
    const float* b_ih     = (const float*)d_in[9];
    const float* b_hh     = (const float*)d_in[10];
    const float* Wl       = (const float*)d_in[11];
    const float* Wr       = (const float*)d_in[12];
    const float* att_a    = (const float*)d_in[13];
    const float* gat_bias = (const float*)d_in[14];
    const float* conv1_w  = (const float*)d_in[15];
    const float* conv1_b  = (const float*)d_in[16];
    const float* conv2_w  = (const float*)d_in[17];
    const float* conv2_b  = (const float*)d_in[18];
    const float* Wc       = (const float*)d_in[19];
    const float* bc       = (const float*)d_in[20];
    const float* Wp       = (const float*)d_in[21];
    const float* bp       = (const float*)d_in[22];
    const float* Wh       = (const float*)d_in[23];
    const float* bh       = (const float*)d_in[24];
    const float* Wo       = (const float*)d_in[25];
    const float* bo       = (const float*)d_in[26];
    const float* Wa       = (const float*)d_in[27];
    const float* ba       = (const float*)d_in[28];

    float* out = (float*)d_out;                 // [0,128): out ; [128,400128): alpha
    float* w   = (float*)d_ws;

    // ws layout (float units)
    size_t off = 0;
    __hip_bfloat16* gx = (__hip_bfloat16*)(w + off); off += (size_t)CN*T_*G3/2; // 24,576,000 f-equiv
    float* hbuf   = w + off; off += (size_t)BN_*H_;       // 2,048,000
    float* xl     = w + off; off += (size_t)BN_*HC;       // 10,240,000
    float* xr     = w + off; off += (size_t)BN_*HC;       // 10,240,000
    float* pbuf   = w + off; off += (size_t)ETOT*HEADS;   // 400,000
    unsigned* segmax = (unsigned*)(w + off); off += (size_t)BN_*HEADS; // 80,000
    float* segsum = w + off; off += (size_t)BN_*HEADS;    // 80,000
    float* nodeo  = w + off; off += (size_t)B_*HC;        // 10,240
    float* c1     = w + off; off += (size_t)16*32*16*16;  // 131,072
    float* c2     = w + off; off += (size_t)16*64*8*8;    // 65,536
    float* tacc   = w + off; off += (size_t)B_*H_;        // 2,048
    float* WihT   = w + off; off += (size_t)H_*G3;        // 49,152
    float* WhhT   = w + off; off += (size_t)H_*G3;        // 49,152
    // total ~48M floats = ~183 MB

    k_transpose<<<(G3*H_+255)/256, 256, 0, stream>>>(W_ih, W_hh, WihT, WhhT);
    k_init<<<(BN_*HEADS+255)/256, 256, 0, stream>>>(segmax, segsum, nodeo, tacc);

    for(int c=0;c<CHUNKS;c++){
        k_gx <<<CN*T_/32, 256, 0, stream>>>(obs, W_nbrs, b_nbrs, WihT, b_ih, gx, c*CN*T_);
        k_gru<<<CN/16,    256, 0, stream>>>(gx, WhhT, b_hh, hbuf, c*CN);
    }
    k_xlxr<<<dim3(BN_/64, (2*HC)/64), 256, 0, stream>>>(hbuf, Wl, Wr, xl, xr);
    k_logits<<<ETOT/4, 256, 0, stream>>>(xl, xr, edges, att_a, pbuf);
    k_segmax<<<(ETOT*HEADS+255)/256, 256, 0, stream>>>(pbuf, edges, segmax);
    k_expsum<<<(ETOT*HEADS+255)/256, 256, 0, stream>>>(pbuf, edges, segmax, segsum);
    k_alpha <<<(ETOT*HEADS+255)/256, 256, 0, stream>>>(pbuf, segsum, edges, xl, out+128, nodeo);
    k_conv1<<<(16*32*16*16)/256, 256, 0, stream>>>(obs_map, conv1_w, conv1_b, c1);
    k_conv2<<<(16*64*8*8)/256, 256, 0, stream>>>(c1, conv2_w, conv2_b, c2);
    k_tembacc<<<16*8, 256, 0, stream>>>(c2, Wc, tacc);
    k_head<<<1, 256, 0, stream>>>(nodeo, gat_bias, tacc, bc, phase,
                                  Wp, bp, Wh, bh, Wo, bo, Wa, ba, out);
}

// Round 2
// 559.324 us; speedup vs baseline: 2.8124x; 2.8124x over previous
//
#include <hip/hip_runtime.h>
#include <hip/hip_bf16.h>
#include <math.h>

#define B_    16
#define N_    1000
#define BN_   16000
#define T_    16
#define FO    16
#define H_    128
#define G3    384       // 3*H
#define HEADS 5
#define HC    640       // heads*H
#define E_    4000
#define EG    64000     // B*E
#define ETOT  80000     // EG + BN self loops
#define P_    8
#define A_    8
#define CHUNKS 2
#define CN    8000      // nodes per chunk
#define NEG_SLOPE 0.2f

typedef __attribute__((ext_vector_type(8))) short bf16x8;
typedef __attribute__((ext_vector_type(4))) float f32x4;

__device__ __forceinline__ float fsigmoid(float x){ return 1.0f/(1.0f + __expf(-x)); }
__device__ __forceinline__ float ftanh_(float x){ return 2.0f/(1.0f + __expf(-2.0f*x)) - 1.0f; }
__device__ __forceinline__ float bf2f(unsigned short u){ return __uint_as_float(((unsigned)u)<<16); }
__device__ __forceinline__ unsigned short f2bf(float x){
    unsigned u = __float_as_uint(x);
    unsigned r = (u + 0x7FFFu + ((u>>16)&1u)) >> 16;
    return (unsigned short)r;
}
__device__ __forceinline__ void f4a(float4 v, float* a){ a[0]=v.x; a[1]=v.y; a[2]=v.z; a[3]=v.w; }

// ---------------- K_prep: W_ih, W_hh f32 -> bf16 (same row-major [384][128]) ------------
__global__ void k_prep(const float* __restrict__ Wih, const float* __restrict__ Whh,
                       unsigned short* __restrict__ Wihb, unsigned short* __restrict__ Whhb){
    int i = blockIdx.x*256 + threadIdx.x;
    if(i < G3*H_){ Wihb[i] = f2bf(Wih[i]); Whhb[i] = f2bf(Whh[i]); }
}

// ---------------- K_init: zero/seed atomics buffers ----------------
__global__ void k_init(unsigned* __restrict__ segmax, float* __restrict__ segsum,
                       float* __restrict__ node_out, float* __restrict__ tacc){
    int i = blockIdx.x*256 + threadIdx.x;
    if(i < BN_*HEADS){ segmax[i] = 0x007FFFFFu; segsum[i] = 0.0f; } // encode(-inf)
    if(i < B_*HC)  node_out[i] = 0.0f;
    if(i < B_*H_)  tacc[i] = 0.0f;
}

// ============ K1: gx = relu(obs@Wn+bn)@WihT + bih, MFMA bf16 version ============
// Block: 64 rows x 384 cols, 4 waves. Wave w owns col tiles {2w,2w+1,8+2w,8+2w+1,16+2w,16+2w+1}.
// Swapped operands: D = Wih(A) * X^T(B) -> lane: node=l&15, c=(l>>4)*4+v within tile.
__global__ __launch_bounds__(256,2) void k_gx(const float* __restrict__ obs,
        const float* __restrict__ Wn, const float* __restrict__ bn,
        const unsigned short* __restrict__ Wihb, const float* __restrict__ bih,
        unsigned short* __restrict__ gxout, int chunk_row_base){
    __shared__ float sObs[64][17];
    __shared__ float sWn[FO*H_];
    __shared__ unsigned short sX[64*128];   // bf16, 16B-chunk XOR-swizzled
    int t = threadIdx.x;
    int w = t>>6, lane = t&63, lq = lane>>4, lm = lane&15;
    const int tm[6] = {2*w, 2*w+1, 8+2*w, 8+2*w+1, 16+2*w, 16+2*w+1};

    // persistent W fragments: lane holds Wih[16*tm[i]+lm][32kt + lq*8 .. +8]
    bf16x8 wf[6][4];
    #pragma unroll
    for(int i=0;i<6;i++){
        int row = tm[i]*16 + lm;
        #pragma unroll
        for(int kt=0;kt<4;kt++)
            wf[i][kt] = *(const bf16x8*)&Wihb[row*H_ + kt*32 + lq*8];
    }
    float bias[6][4];
    #pragma unroll
    for(int i=0;i<6;i++){
        f32x4 bv = *(const f32x4*)&bih[tm[i]*16 + lq*4];
        #pragma unroll
        for(int v=0;v<4;v++) bias[i][v] = bv[v];
    }

    int rowBase = chunk_row_base + blockIdx.x*64;
    for(int i=t;i<64*16;i+=256) sObs[i>>4][i&15] = obs[(size_t)(rowBase+(i>>4))*FO + (i&15)];
    for(int i=t;i<FO*H_;i+=256) sWn[i] = Wn[i];
    __syncthreads();

    { // X = relu(obs@Wn+bn): thread: row t&63, 32 cols
        int r = t&63, c0 = (t>>6)*32;
        float a[32];
        #pragma unroll
        for(int j=0;j<32;j++) a[j] = bn[c0+j];
        #pragma unroll
        for(int k=0;k<FO;k++){
            float ov = sObs[r][k];
            #pragma unroll
            for(int j=0;j<32;j++) a[j] = fmaf(ov, sWn[k*H_+c0+j], a[j]);
        }
        #pragma unroll
        for(int j4=0;j4<4;j4++){
            unsigned pk0 = (unsigned)f2bf(fmaxf(a[j4*8+0],0.f)) | ((unsigned)f2bf(fmaxf(a[j4*8+1],0.f))<<16);
            unsigned pk1 = (unsigned)f2bf(fmaxf(a[j4*8+2],0.f)) | ((unsigned)f2bf(fmaxf(a[j4*8+3],0.f))<<16);
            unsigned pk2 = (unsigned)f2bf(fmaxf(a[j4*8+4],0.f)) | ((unsigned)f2bf(fmaxf(a[j4*8+5],0.f))<<16);
            unsigned pk3 = (unsigned)f2bf(fmaxf(a[j4*8+6],0.f)) | ((unsigned)f2bf(fmaxf(a[j4*8+7],0.f))<<16);
            int chunk = ((c0>>3) + j4) ^ (r&7);
            *(uint4*)&sX[r*128 + chunk*8] = make_uint4(pk0,pk1,pk2,pk3);
        }
    }
    __syncthreads();

    for(int g=0; g<4; g++){
        bf16x8 xb[4];
        int row = g*16 + lm;
        #pragma unroll
        for(int kt=0;kt<4;kt++){
            int chunk = (4*kt + lq) ^ (row&7);
            xb[kt] = *(const bf16x8*)&sX[row*128 + chunk*8];
        }
        f32x4 acc[6];
        #pragma unroll
        for(int i=0;i<6;i++) acc[i] = (f32x4){0.f,0.f,0.f,0.f};
        #pragma unroll
        for(int kt=0;kt<4;kt++){
            #pragma unroll
            for(int i=0;i<6;i++)
                acc[i] = __builtin_amdgcn_mfma_f32_16x16x32_bf16(wf[i][kt], xb[kt], acc[i], 0,0,0);
        }
        size_t orow = (size_t)(blockIdx.x*64 + g*16 + lm)*G3;
        #pragma unroll
        for(int i=0;i<6;i++){
            ushort4 o;
            o.x = f2bf(acc[i][0] + bias[i][0]);
            o.y = f2bf(acc[i][1] + bias[i][1]);
            o.z = f2bf(acc[i][2] + bias[i][2]);
            o.w = f2bf(acc[i][3] + bias[i][3]);
            *(ushort4*)&gxout[orow + tm[i]*16 + lq*4] = o;
        }
    }
}

// ============ K2: GRU recurrence, MFMA bf16. 16 nodes/block, 4 waves ============
// Wave w owns h cols [32w,32w+32): tiles r{2w,2w+1}, z{8+2w,+1}, n{16+2w,+1}.
// h kept f32 in regs (ho); bf16 copy in swizzled LDS is the MFMA B operand.
__global__ __launch_bounds__(256,2) void k_gru(const unsigned short* __restrict__ gx,
        const unsigned short* __restrict__ Whhb, const float* __restrict__ bhh,
        float* __restrict__ hout, int chunk_node_base){
    __shared__ unsigned short sH[2][16*128];   // bf16, double-buffered, swizzled
    int t = threadIdx.x;
    int w = t>>6, lane = t&63, lq = lane>>4, lm = lane&15;
    const int tm[6] = {2*w, 2*w+1, 8+2*w, 8+2*w+1, 16+2*w, 16+2*w+1};

    bf16x8 wf[6][4];
    #pragma unroll
    for(int i=0;i<6;i++){
        int row = tm[i]*16 + lm;
        #pragma unroll
        for(int kt=0;kt<4;kt++)
            wf[i][kt] = *(const bf16x8*)&Whhb[row*H_ + kt*32 + lq*8];
    }
    float bias[6][4];
    #pragma unroll
    for(int i=0;i<6;i++){
        f32x4 bv = *(const f32x4*)&bhh[tm[i]*16 + lq*4];
        #pragma unroll
        for(int v=0;v<4;v++) bias[i][v] = bv[v];
    }

    for(int i=t;i<1024;i+=256) ((unsigned*)sH)[i] = 0;   // zero both buffers (4KB each)
    float ho[2][4] = {{0.f,0.f,0.f,0.f},{0.f,0.f,0.f,0.f}};
    __syncthreads();

    int nodeBase = blockIdx.x*16;   // chunk-local
    const unsigned short* gxrow0 = &gx[(size_t)(nodeBase + lm)*T_*G3];
    int colb = 32*w + lq*4;
    int p = 0;
    for(int step=0; step<T_; step++){
        // gx loads (early)
        const unsigned short* gr = gxrow0 + (size_t)step*G3;
        ushort4 xr[2], xz[2], xn[2];
        xr[0] = *(const ushort4*)&gr[colb];       xr[1] = *(const ushort4*)&gr[colb+16];
        xz[0] = *(const ushort4*)&gr[colb+128];   xz[1] = *(const ushort4*)&gr[colb+144];
        xn[0] = *(const ushort4*)&gr[colb+256];   xn[1] = *(const ushort4*)&gr[colb+272];
        // h B-fragments from LDS
        bf16x8 hb[4];
        #pragma unroll
        for(int kt=0;kt<4;kt++){
            int chunk = (4*kt + lq) ^ (lm&7);
            hb[kt] = *(const bf16x8*)&sH[p][lm*128 + chunk*8];
        }
        f32x4 acc[6];
        #pragma unroll
        for(int i=0;i<6;i++) acc[i] = (f32x4){0.f,0.f,0.f,0.f};
        #pragma unroll
        for(int kt=0;kt<4;kt++){
            #pragma unroll
            for(int i=0;i<6;i++)
                acc[i] = __builtin_amdgcn_mfma_f32_16x16x32_bf16(wf[i][kt], hb[kt], acc[i], 0,0,0);
        }
        // gates: lane has node lm, cols 32w+16u+lq*4+v
        #pragma unroll
        for(int u=0;u<2;u++){
            unsigned short hw0,hw1,hw2,hw3;
            {
                unsigned short xra[4]={xr[u].x,xr[u].y,xr[u].z,xr[u].w};
                unsigned short xza[4]={xz[u].x,xz[u].y,xz[u].z,xz[u].w};
                unsigned short xna[4]={xn[u].x,xn[u].y,xn[u].z,xn[u].w};
                unsigned short hwa[4];
                #pragma unroll
                for(int v=0;v<4;v++){
                    float hr = acc[0+u][v] + bias[0+u][v];
                    float hz = acc[2+u][v] + bias[2+u][v];
                    float hn = acc[4+u][v] + bias[4+u][v];
                    float r  = fsigmoid(bf2f(xra[v]) + hr);
                    float z  = fsigmoid(bf2f(xza[v]) + hz);
                    float nn = ftanh_(bf2f(xna[v]) + r*hn);
                    float hv = (1.f - z)*nn + z*ho[u][v];
                    ho[u][v] = hv;
                    hwa[v] = f2bf(hv);
                }
                hw0=hwa[0]; hw1=hwa[1]; hw2=hwa[2]; hw3=hwa[3];
            }
            int chunk = (4*w + 2*u + (lq>>1)) ^ (lm&7);
            int half = lq & 1;
            *(uint2*)&sH[p^1][lm*128 + chunk*8 + half*4] =
                make_uint2((unsigned)hw0 | ((unsigned)hw1<<16),
                           (unsigned)hw2 | ((unsigned)hw3<<16));
        }
        __syncthreads();
        p ^= 1;
    }
    int node = chunk_node_base + nodeBase + lm;
    #pragma unroll
    for(int u=0;u<2;u++){
        f32x4 hv = (f32x4){ho[u][0], ho[u][1], ho[u][2], ho[u][3]};
        *(f32x4*)&hout[(size_t)node*H_ + 32*w + 16*u + lq*4] = hv;
    }
}

// ---------------- K3: xl = h@Wl, xr = h@Wr  (M=16000, N=2x640, K=128) ----------------
__global__ __launch_bounds__(256) void k_xlxr(const float* __restrict__ h,
        const float* __restrict__ Wl, const float* __restrict__ Wr,
        float* __restrict__ xl, float* __restrict__ xr){
    __shared__ float sH[64][132];
    int t = threadIdx.x;
    int r0 = blockIdx.x*64;
    int cblk = blockIdx.y*64;      // 0..1279 over [Wl|Wr]
    for(int i=t; i<64*32; i+=256){
        int row = i >> 5, kq = (i & 31)*4;
        *(float4*)&sH[row][kq] = *(const float4*)&h[(size_t)(r0+row)*H_ + kq];
    }
    __syncthreads();
    int rr = (t & 15)*4, cc = cblk + (t >> 4)*4;
    const float* W; float* Out; int cw;
    if(cc < HC){ W = Wl; Out = xl; cw = cc; } else { W = Wr; Out = xr; cw = cc - HC; }
    float acc[4][4];
    #pragma unroll
    for(int i=0;i<4;i++){
        #pragma unroll
        for(int j=0;j<4;j++) acc[i][j]=0.f;
    }
    for(int k=0;k<H_;k+=4){
        float ha[4][4];
        #pragma unroll
        for(int i=0;i<4;i++) f4a(*(const float4*)&sH[rr+i][k], ha[i]);
        #pragma unroll
        for(int kk=0;kk<4;kk++){
            float4 w = *(const float4*)&W[(size_t)(k+kk)*HC + cw];
            #pragma unroll
            for(int i=0;i<4;i++){
                float hv = ha[i][kk];
                acc[i][0]=fmaf(hv,w.x,acc[i][0]); acc[i][1]=fmaf(hv,w.y,acc[i][1]);
                acc[i][2]=fmaf(hv,w.z,acc[i][2]); acc[i][3]=fmaf(hv,w.w,acc[i][3]);
            }
        }
    }
    #pragma unroll
    for(int i=0;i<4;i++)
        *(float4*)&Out[(size_t)(r0+rr+i)*HC + cw] =
            make_float4(acc[i][0],acc[i][1],acc[i][2],acc[i][3]);
}

// ---------------- edge src/dst helper ----------------
__device__ __forceinline__ void edge_sd(int e, const int* __restrict__ edges, int* src, int* dst){
    if(e < EG){
        int b = e / E_, j = e - b*E_;
        *src = edges[(b*2+0)*E_ + j] + b*N_;
        *dst = edges[(b*2+1)*E_ + j] + b*N_;
    } else { *src = *dst = e - EG; }
}

// ---------------- K4: GATv2 edge logits (one wave per edge) ----------------
__global__ __launch_bounds__(256) void k_logits(const float* __restrict__ xl,
        const float* __restrict__ xr, const int* __restrict__ edges,
        const float* __restrict__ atta, float* __restrict__ logits){
    __shared__ float sA[HEADS*H_];
    int t = threadIdx.x;
    for(int i=t;i<HEADS*H_;i+=256) sA[i]=atta[i];
    __syncthreads();
    int lane = t & 63;
    int e = blockIdx.x*4 + (t >> 6);
    if(e >= ETOT) return;
    int src, dst; edge_sd(e, edges, &src, &dst);
    const float* xls = &xl[(size_t)src*HC];
    const float* xrd = &xr[(size_t)dst*HC];
    for(int hh=0; hh<HEADS; hh++){
        float s1 = xls[hh*H_+lane]    + xrd[hh*H_+lane];
        float s2 = xls[hh*H_+lane+64] + xrd[hh*H_+lane+64];
        s1 = s1 > 0.f ? s1 : NEG_SLOPE*s1;
        s2 = s2 > 0.f ? s2 : NEG_SLOPE*s2;
        float p = s1*sA[hh*H_+lane] + s2*sA[hh*H_+lane+64];
        #pragma unroll
        for(int off=32; off; off>>=1) p += __shfl_xor(p, off);
        if(lane==0) logits[(size_t)e*HEADS+hh] = p;
    }
}

// ---------------- K5a: segment max (monotone-uint float encoding) ----------------
__global__ void k_segmax(const float* __restrict__ logits, const int* __restrict__ edges,
                         unsigned* __restrict__ segmax){
    int idx = blockIdx.x*256 + threadIdx.x;
    if(idx >= ETOT*HEADS) return;
    int e = idx / HEADS, hh = idx - e*HEADS;
    int src, dst; edge_sd(e, edges, &src, &dst);
    unsigned u = __float_as_uint(logits[idx]);
    u = (u & 0x80000000u) ? ~u : (u | 0x80000000u);
    atomicMax(&segmax[dst*HEADS+hh], u);
}

// ---------------- K5b: p = exp(logit - m), segsum += p ----------------
__global__ void k_expsum(float* __restrict__ pbuf, const int* __restrict__ edges,
                         const unsigned* __restrict__ segmax, float* __restrict__ segsum){
    int idx = blockIdx.x*256 + threadIdx.x;
    if(idx >= ETOT*HEADS) return;
    int e = idx / HEADS, hh = idx - e*HEADS;
    int src, dst; edge_sd(e, edges, &src, &dst);
    unsigned u = segmax[dst*HEADS+hh];
    float m = (u & 0x80000000u) ? __uint_as_float(u ^ 0x80000000u) : __uint_as_float(~u);
    float p = __expf(pbuf[idx] - m);
    pbuf[idx] = p;
    atomicAdd(&segsum[dst*HEADS+hh], p);
}

// ---------------- K5c: alpha out + sparse node_out accumulation ----------------
__global__ void k_alpha(const float* __restrict__ pbuf, const float* __restrict__ segsum,
                        const int* __restrict__ edges, const float* __restrict__ xl,
                        float* __restrict__ out_alpha, float* __restrict__ node_out){
    int idx = blockIdx.x*256 + threadIdx.x;
    if(idx >= ETOT*HEADS) return;
    int e = idx / HEADS, hh = idx - e*HEADS;
    int src, dst; edge_sd(e, edges, &src, &dst);
    float a = pbuf[idx] / segsum[dst*HEADS+hh];
    out_alpha[idx] = a;
    if(dst % N_ == 0){   // only ego nodes b*N feed the head
        int b = dst / N_;
        const float* x = &xl[(size_t)src*HC + hh*H_];
        float* no = &node_out[b*HC + hh*H_];
        for(int c=0;c<H_;c++) atomicAdd(&no[c], a * x[c]);
    }
}

// ---------------- K6: conv1 4->32, 32x32 -> 16x16, stride2 SAME ----------------
__global__ __launch_bounds__(256) void k_conv1(const float* __restrict__ im,
        const float* __restrict__ w, const float* __restrict__ bias, float* __restrict__ outp){
    __shared__ float sW[32*4*9];
    int t = threadIdx.x;
    for(int i=t;i<32*4*9;i+=256) sW[i]=w[i];
    __syncthreads();
    int idx = blockIdx.x*256 + t;
    if(idx >= 16*32*16*16) return;
    int ox = idx & 15, oy = (idx>>4)&15, oc = (idx>>8)&31, b = idx>>13;
    float acc = bias[oc];
    for(int ic=0;ic<4;ic++){
        const float* ip = &im[(size_t)((b*4+ic)*32)*32];
        const float* wp = &sW[(oc*4+ic)*9];
        #pragma unroll
        for(int ky=0;ky<3;ky++){
            int iy = oy*2+ky; if(iy>=32) continue;
            #pragma unroll
            for(int kx=0;kx<3;kx++){
                int ix = ox*2+kx; if(ix>=32) continue;
                acc = fmaf(ip[iy*32+ix], wp[ky*3+kx], acc);
            }
        }
    }
    outp[idx] = fmaxf(acc, 0.f);
}

// ---------------- K7: conv2 32->64, 16x16 -> 8x8 ----------------
__global__ __launch_bounds__(256) void k_conv2(const float* __restrict__ c1,
        const float* __restrict__ w, const float* __restrict__ bias, float* __restrict__ outp){
    int idx = blockIdx.x*256 + threadIdx.x;
    if(idx >= 16*64*8*8) return;
    int ox = idx & 7, oy = (idx>>3)&7, oc = (idx>>6)&63, b = idx>>12;
    float acc = bias[oc];
    for(int ic=0;ic<32;ic++){
        const float* ip = &c1[(size_t)((b*32+ic)*16)*16];
        const float* wp = &w[(oc*32+ic)*9];
        #pragma unroll
        for(int ky=0;ky<3;ky++){
            int iy = oy*2+ky; if(iy>=16) continue;
            #pragma unroll
            for(int kx=0;kx<3;kx++){
                int ix = ox*2+kx; if(ix>=16) continue;
                acc = fmaf(ip[iy*16+ix], wp[ky*3+kx], acc);
            }
        }
    }
    outp[idx] = fmaxf(acc, 0.f);
}

// ---------------- K8: temb partial GEMM [16,4096]@[4096,128] via k-split atomics ------
__global__ void k_tembacc(const float* __restrict__ c2, const float* __restrict__ Wc,
                          float* __restrict__ tacc){
    int t = threadIdx.x;
    int b = blockIdx.x >> 3, ks = blockIdx.x & 7;
    int j = t & 127, sub = t >> 7;
    int k0 = ks*512 + sub*256;
    const float* cp = &c2[(size_t)b*4096];
    float acc = 0.f;
    for(int k=k0;k<k0+256;k++) acc = fmaf(cp[k], Wc[(size_t)k*H_+j], acc);
    atomicAdd(&tacc[b*H_+j], acc);
}

// ---------------- K9: head ----------------
__global__ __launch_bounds__(256) void k_head(const float* __restrict__ node_out,
        const float* __restrict__ gat_bias, const float* __restrict__ tacc,
        const float* __restrict__ bc, const float* __restrict__ phase,
        const float* __restrict__ Wp, const float* __restrict__ bp,
        const float* __restrict__ Wh, const float* __restrict__ bh,
        const float* __restrict__ Wo, const float* __restrict__ bo,
        const float* __restrict__ Wa, const float* __restrict__ ba,
        float* __restrict__ out){
    __shared__ float sF[16][268];
    __shared__ float sHid[16][132];
    int t = threadIdx.x;
    for(int i=t;i<B_*H_;i+=256){
        int b=i>>7, c=i&127;
        float s=0.f;
        #pragma unroll
        for(int hh=0;hh<HEADS;hh++) s += node_out[b*HC + hh*H_ + c];
        sF[b][c] = s*(1.0f/HEADS) + gat_bias[c];
    }
    for(int i=t;i<B_*H_;i+=256){
        int b=i>>7, c=i&127;
        sF[b][128+c] = fmaxf(tacc[i] + bc[c], 0.f);
    }
    if(t < B_*P_){
        int b=t>>3, p=t&7;
        float s=bp[p];
        #pragma unroll
        for(int q=0;q<P_;q++) s = fmaf(phase[b*P_+q], Wp[q*P_+p], s);
        sF[b][256+p] = fmaxf(s, 0.f);
    }
    __syncthreads();
    for(int i=t;i<B_*H_;i+=256){
        int b=i>>7, j=i&127;
        float s=bh[j];
        for(int k=0;k<2*H_+P_;k++) s = fmaf(sF[b][k], Wh[k*H_+j], s);
        sHid[b][j]=fmaxf(s,0.f);
    }
    __syncthreads();
    if(t < B_*A_){
        int b=t>>3, a=t&7;
        float v=bo[0], ad=ba[a];
        for(int k=0;k<H_;k++){ float hv=sHid[b][k]; v = fmaf(hv,Wo[k],v); ad = fmaf(hv,Wa[k*A_+a],ad); }
        float m = ad;
        m += __shfl_xor(m,1); m += __shfl_xor(m,2); m += __shfl_xor(m,4);
        m *= 0.125f;
        out[b*A_+a] = v + ad - m;
    }
}

extern "C" void kernel_launch(void* const* d_in, const int* in_sizes, int n_in,
                              void* d_out, int out_size, void* d_ws, size_t ws_size,
                              hipStream_t stream) {
    (void)in_sizes; (void)n_in; (void)out_size; (void)ws_size;
    const float* obs      = (const float*)d_in[0];
    const float* phase    = (const float*)d_in[1];
    const float* obs_map  = (const float*)d_in[2];
    const int*   edges    = (const int*)  d_in[3];
    const float* W_nbrs   = (const float*)d_in[5];
    const float* b_nbrs   = (const float*)d_in[6];
    const float* W_ih     = (const float*)d_in[7];
    const float* W_hh     = (const float*)d_in[8];
    const float* b_ih     = (const float*)d_in[9];
    const float* b_hh     = (const float*)d_in[10];
    const float* Wl       = (const float*)d_in[11];
    const float* Wr       = (const float*)d_in[12];
    const float* att_a    = (const float*)d_in[13];
    const float* gat_bias = (const float*)d_in[14];
    const float* conv1_w  = (const float*)d_in[15];
    const float* conv1_b  = (const float*)d_in[16];
    const float* conv2_w  = (const float*)d_in[17];
    const float* conv2_b  = (const float*)d_in[18];
    const float* Wc       = (const float*)d_in[19];
    const float* bc       = (const float*)d_in[20];
    const float* Wp       = (const float*)d_in[21];
    const float* bp       = (const float*)d_in[22];
    const float* Wh       = (const float*)d_in[23];
    const float* bh       = (const float*)d_in[24];
    const float* Wo       = (const float*)d_in[25];
    const float* bo       = (const float*)d_in[26];
    const float* Wa       = (const float*)d_in[27];
    const float* ba       = (const float*)d_in[28];

    float* out = (float*)d_out;                 // [0,128): out ; [128,400128): alpha
    float* w   = (float*)d_ws;

    // ws layout (float units)
    size_t off = 0;
    unsigned short* gx = (unsigned short*)(w + off); off += (size_t)CN*T_*G3/2; // bf16
    float* hbuf   = w + off; off += (size_t)BN_*H_;
    float* xl     = w + off; off += (size_t)BN_*HC;
    float* xr     = w + off; off += (size_t)BN_*HC;
    float* pbuf   = w + off; off += (size_t)ETOT*HEADS;
    unsigned* segmax = (unsigned*)(w + off); off += (size_t)BN_*HEADS;
    float* segsum = w + off; off += (size_t)BN_*HEADS;
    float* nodeo  = w + off; off += (size_t)B_*HC;
    float* c1     = w + off; off += (size_t)16*32*16*16;
    float* c2     = w + off; off += (size_t)16*64*8*8;
    float* tacc   = w + off; off += (size_t)B_*H_;
    unsigned short* Wihb = (unsigned short*)(w + off); off += (size_t)H_*G3/2;
    unsigned short* Whhb = (unsigned short*)(w + off); off += (size_t)H_*G3/2;

    k_prep<<<(G3*H_+255)/256, 256, 0, stream>>>(W_ih, W_hh, Wihb, Whhb);
    k_init<<<(BN_*HEADS+255)/256, 256, 0, stream>>>(segmax, segsum, nodeo, tacc);

    for(int c=0;c<CHUNKS;c++){
        k_gx <<<CN*T_/64, 256, 0, stream>>>(obs, W_nbrs, b_nbrs, Wihb, b_ih, gx, c*CN*T_);
        k_gru<<<CN/16,    256, 0, stream>>>(gx, Whhb, b_hh, hbuf, c*CN);
    }
    k_xlxr<<<dim3(BN_/64, (2*HC)/64), 256, 0, stream>>>(hbuf, Wl, Wr, xl, xr);
    k_logits<<<ETOT/4, 256, 0, stream>>>(xl, xr, edges, att_a, pbuf);
    k_segmax<<<(ETOT*HEADS+255)/256, 256, 0, stream>>>(pbuf, edges, segmax);
    k_expsum<<<(ETOT*HEADS+255)/256, 256, 0, stream>>>(pbuf, edges, segmax, segsum);
    k_alpha <<<(ETOT*HEADS+255)/256, 256, 0, stream>>>(pbuf, segsum, edges, xl, out+128, nodeo);
    k_conv1<<<(16*32*16*16)/256, 256, 0, stream>>>(obs_map, conv1_w, conv1_b, c1);
    k_conv2<<<(16*64*8*8)/256, 256, 0, stream>>>(c1, conv2_w, conv2_b, c2);
    k_tembacc<<<16*8, 256, 0, stream>>>(c2, Wc, tacc);
    k_head<<<1, 256, 0, stream>>>(nodeo, gat_bias, tacc, bc, phase,
                                  Wp, bp, Wh, bh, Wo, bo, Wa, ba, out);
}

// Round 3
// 470.033 us; speedup vs baseline: 3.3467x; 1.1900x over previous
//
#include <hip/hip_runtime.h>
#include <hip/hip_bf16.h>
#include <math.h>

#define B_    16
#define N_    1000
#define BN_   16000
#define T_    16
#define FO    16
#define H_    128
#define G3    384       // 3*H
#define HEADS 5
#define HC    640       // heads*H
#define E_    4000
#define EG    64000     // B*E
#define ETOT  80000     // EG + BN self loops
#define P_    8
#define A_    8
#define CHUNKS 2
#define CN    8000      // nodes per chunk
#define NEG_SLOPE 0.2f

typedef __attribute__((ext_vector_type(8))) short bf16x8;
typedef __attribute__((ext_vector_type(4))) float f32x4;

__device__ __forceinline__ float fsigmoid(float x){ return 1.0f/(1.0f + __expf(-x)); }
__device__ __forceinline__ float ftanh_(float x){ return 2.0f/(1.0f + __expf(-2.0f*x)) - 1.0f; }
__device__ __forceinline__ float bf2f(unsigned short u){ return __uint_as_float(((unsigned)u)<<16); }
__device__ __forceinline__ unsigned short f2bf(float x){
    unsigned u = __float_as_uint(x);
    unsigned r = (u + 0x7FFFu + ((u>>16)&1u)) >> 16;
    return (unsigned short)r;
}
__device__ __forceinline__ void f4a(float4 v, float* a){ a[0]=v.x; a[1]=v.y; a[2]=v.z; a[3]=v.w; }

// ---------------- K_prep: bf16 weight prep ----------------
// Wih/Whh f32 -> bf16 row-major [384][128]; WT[1280][128] = [Wl|Wr]^T bf16.
__global__ void k_prep(const float* __restrict__ Wih, const float* __restrict__ Whh,
                       const float* __restrict__ Wl, const float* __restrict__ Wr,
                       unsigned short* __restrict__ Wihb, unsigned short* __restrict__ Whhb,
                       unsigned short* __restrict__ WTb){
    int i = blockIdx.x*256 + threadIdx.x;
    if(i < G3*H_){ Wihb[i] = f2bf(Wih[i]); Whhb[i] = f2bf(Whh[i]); }
    if(i < 2*HC*H_){
        int c = i >> 7, k = i & 127;
        float v = (c < HC) ? Wl[(size_t)k*HC + c] : Wr[(size_t)k*HC + (c-HC)];
        WTb[i] = f2bf(v);
    }
}

// ---------------- K_init: zero/seed atomics buffers ----------------
__global__ void k_init(unsigned* __restrict__ segmax, float* __restrict__ segsum,
                       float* __restrict__ node_out, float* __restrict__ tacc){
    int i = blockIdx.x*256 + threadIdx.x;
    if(i < BN_*HEADS){ segmax[i] = 0x007FFFFFu; segsum[i] = 0.0f; } // encode(-inf)
    if(i < B_*HC)  node_out[i] = 0.0f;
    if(i < B_*H_)  tacc[i] = 0.0f;
}

// ============ K1: gx = relu(obs@Wn+bn)@WihT + bih, MFMA bf16 ============
__global__ __launch_bounds__(256,2) void k_gx(const float* __restrict__ obs,
        const float* __restrict__ Wn, const float* __restrict__ bn,
        const unsigned short* __restrict__ Wihb, const float* __restrict__ bih,
        unsigned short* __restrict__ gxout, int chunk_row_base){
    __shared__ float sObs[64][17];
    __shared__ float sWn[FO*H_];
    __shared__ unsigned short sX[64*128];   // bf16, 16B-chunk XOR-swizzled
    int t = threadIdx.x;
    int w = t>>6, lane = t&63, lq = lane>>4, lm = lane&15;
    const int tm[6] = {2*w, 2*w+1, 8+2*w, 8+2*w+1, 16+2*w, 16+2*w+1};

    bf16x8 wf[6][4];
    #pragma unroll
    for(int i=0;i<6;i++){
        int row = tm[i]*16 + lm;
        #pragma unroll
        for(int kt=0;kt<4;kt++)
            wf[i][kt] = *(const bf16x8*)&Wihb[row*H_ + kt*32 + lq*8];
    }
    float bias[6][4];
    #pragma unroll
    for(int i=0;i<6;i++){
        f32x4 bv = *(const f32x4*)&bih[tm[i]*16 + lq*4];
        #pragma unroll
        for(int v=0;v<4;v++) bias[i][v] = bv[v];
    }

    int rowBase = chunk_row_base + blockIdx.x*64;
    for(int i=t;i<64*16;i+=256) sObs[i>>4][i&15] = obs[(size_t)(rowBase+(i>>4))*FO + (i&15)];
    for(int i=t;i<FO*H_;i+=256) sWn[i] = Wn[i];
    __syncthreads();

    { // X = relu(obs@Wn+bn)
        int r = t&63, c0 = (t>>6)*32;
        float a[32];
        #pragma unroll
        for(int j=0;j<32;j++) a[j] = bn[c0+j];
        #pragma unroll
        for(int k=0;k<FO;k++){
            float ov = sObs[r][k];
            #pragma unroll
            for(int j=0;j<32;j++) a[j] = fmaf(ov, sWn[k*H_+c0+j], a[j]);
        }
        #pragma unroll
        for(int j4=0;j4<4;j4++){
            unsigned pk0 = (unsigned)f2bf(fmaxf(a[j4*8+0],0.f)) | ((unsigned)f2bf(fmaxf(a[j4*8+1],0.f))<<16);
            unsigned pk1 = (unsigned)f2bf(fmaxf(a[j4*8+2],0.f)) | ((unsigned)f2bf(fmaxf(a[j4*8+3],0.f))<<16);
            unsigned pk2 = (unsigned)f2bf(fmaxf(a[j4*8+4],0.f)) | ((unsigned)f2bf(fmaxf(a[j4*8+5],0.f))<<16);
            unsigned pk3 = (unsigned)f2bf(fmaxf(a[j4*8+6],0.f)) | ((unsigned)f2bf(fmaxf(a[j4*8+7],0.f))<<16);
            int chunk = ((c0>>3) + j4) ^ (r&7);
            *(uint4*)&sX[r*128 + chunk*8] = make_uint4(pk0,pk1,pk2,pk3);
        }
    }
    __syncthreads();

    for(int g=0; g<4; g++){
        bf16x8 xb[4];
        int row = g*16 + lm;
        #pragma unroll
        for(int kt=0;kt<4;kt++){
            int chunk = (4*kt + lq) ^ (row&7);
            xb[kt] = *(const bf16x8*)&sX[row*128 + chunk*8];
        }
        f32x4 acc[6];
        #pragma unroll
        for(int i=0;i<6;i++) acc[i] = (f32x4){0.f,0.f,0.f,0.f};
        #pragma unroll
        for(int kt=0;kt<4;kt++){
            #pragma unroll
            for(int i=0;i<6;i++)
                acc[i] = __builtin_amdgcn_mfma_f32_16x16x32_bf16(wf[i][kt], xb[kt], acc[i], 0,0,0);
        }
        size_t orow = (size_t)(blockIdx.x*64 + g*16 + lm)*G3;
        #pragma unroll
        for(int i=0;i<6;i++){
            ushort4 o;
            o.x = f2bf(acc[i][0] + bias[i][0]);
            o.y = f2bf(acc[i][1] + bias[i][1]);
            o.z = f2bf(acc[i][2] + bias[i][2]);
            o.w = f2bf(acc[i][3] + bias[i][3]);
            *(ushort4*)&gxout[orow + tm[i]*16 + lq*4] = o;
        }
    }
}

// ============ K2: GRU recurrence, MFMA bf16. h output now bf16 ============
__global__ __launch_bounds__(256,2) void k_gru(const unsigned short* __restrict__ gx,
        const unsigned short* __restrict__ Whhb, const float* __restrict__ bhh,
        unsigned short* __restrict__ hout, int chunk_node_base){
    __shared__ unsigned short sH[2][16*128];   // bf16, double-buffered, swizzled
    int t = threadIdx.x;
    int w = t>>6, lane = t&63, lq = lane>>4, lm = lane&15;
    const int tm[6] = {2*w, 2*w+1, 8+2*w, 8+2*w+1, 16+2*w, 16+2*w+1};

    bf16x8 wf[6][4];
    #pragma unroll
    for(int i=0;i<6;i++){
        int row = tm[i]*16 + lm;
        #pragma unroll
        for(int kt=0;kt<4;kt++)
            wf[i][kt] = *(const bf16x8*)&Whhb[row*H_ + kt*32 + lq*8];
    }
    float bias[6][4];
    #pragma unroll
    for(int i=0;i<6;i++){
        f32x4 bv = *(const f32x4*)&bhh[tm[i]*16 + lq*4];
        #pragma unroll
        for(int v=0;v<4;v++) bias[i][v] = bv[v];
    }

    for(int i=t;i<1024;i+=256) ((unsigned*)sH)[i] = 0;
    float ho[2][4] = {{0.f,0.f,0.f,0.f},{0.f,0.f,0.f,0.f}};
    __syncthreads();

    int nodeBase = blockIdx.x*16;   // chunk-local
    const unsigned short* gxrow0 = &gx[(size_t)(nodeBase + lm)*T_*G3];
    int colb = 32*w + lq*4;
    int p = 0;
    for(int step=0; step<T_; step++){
        const unsigned short* gr = gxrow0 + (size_t)step*G3;
        ushort4 xr[2], xz[2], xn[2];
        xr[0] = *(const ushort4*)&gr[colb];       xr[1] = *(const ushort4*)&gr[colb+16];
        xz[0] = *(const ushort4*)&gr[colb+128];   xz[1] = *(const ushort4*)&gr[colb+144];
        xn[0] = *(const ushort4*)&gr[colb+256];   xn[1] = *(const ushort4*)&gr[colb+272];
        bf16x8 hb[4];
        #pragma unroll
        for(int kt=0;kt<4;kt++){
            int chunk = (4*kt + lq) ^ (lm&7);
            hb[kt] = *(const bf16x8*)&sH[p][lm*128 + chunk*8];
        }
        f32x4 acc[6];
        #pragma unroll
        for(int i=0;i<6;i++) acc[i] = (f32x4){0.f,0.f,0.f,0.f};
        #pragma unroll
        for(int kt=0;kt<4;kt++){
            #pragma unroll
            for(int i=0;i<6;i++)
                acc[i] = __builtin_amdgcn_mfma_f32_16x16x32_bf16(wf[i][kt], hb[kt], acc[i], 0,0,0);
        }
        #pragma unroll
        for(int u=0;u<2;u++){
            unsigned short hwa[4];
            unsigned short xra[4]={xr[u].x,xr[u].y,xr[u].z,xr[u].w};
            unsigned short xza[4]={xz[u].x,xz[u].y,xz[u].z,xz[u].w};
            unsigned short xna[4]={xn[u].x,xn[u].y,xn[u].z,xn[u].w};
            #pragma unroll
            for(int v=0;v<4;v++){
                float hr = acc[0+u][v] + bias[0+u][v];
                float hz = acc[2+u][v] + bias[2+u][v];
                float hn = acc[4+u][v] + bias[4+u][v];
                float r  = fsigmoid(bf2f(xra[v]) + hr);
                float z  = fsigmoid(bf2f(xza[v]) + hz);
                float nn = ftanh_(bf2f(xna[v]) + r*hn);
                float hv = (1.f - z)*nn + z*ho[u][v];
                ho[u][v] = hv;
                hwa[v] = f2bf(hv);
            }
            int chunk = (4*w + 2*u + (lq>>1)) ^ (lm&7);
            int half = lq & 1;
            *(uint2*)&sH[p^1][lm*128 + chunk*8 + half*4] =
                make_uint2((unsigned)hwa[0] | ((unsigned)hwa[1]<<16),
                           (unsigned)hwa[2] | ((unsigned)hwa[3]<<16));
        }
        __syncthreads();
        p ^= 1;
    }
    int node = chunk_node_base + nodeBase + lm;
    #pragma unroll
    for(int u=0;u<2;u++){
        ushort4 o;
        o.x=f2bf(ho[u][0]); o.y=f2bf(ho[u][1]); o.z=f2bf(ho[u][2]); o.w=f2bf(ho[u][3]);
        *(ushort4*)&hout[(size_t)node*H_ + 32*w + 16*u + lq*4] = o;
    }
}

// ============ K3: xl|xr = h @ [Wl|Wr], MFMA bf16, no LDS ============
// grid (BN/64, 5). Block: 64 nodes x 256 cols; wave w: col tiles y*16 .. (4 tiles).
// Swapped: A = WT rows (out cols), B = h^T (col=node). Outputs bf16.
__global__ __launch_bounds__(256) void k_xlxr(const unsigned short* __restrict__ hb16,
        const unsigned short* __restrict__ WTb,
        unsigned short* __restrict__ xl, unsigned short* __restrict__ xr){
    int t = threadIdx.x;
    int w = t>>6, lane = t&63, lq = lane>>4, lm = lane&15;
    int nblk = blockIdx.x*64;
    int ct0 = blockIdx.y*16 + w*4;          // first col tile of this wave

    bf16x8 wf[4][4];
    #pragma unroll
    for(int i=0;i<4;i++){
        int row = (ct0+i)*16 + lm;          // out col
        #pragma unroll
        for(int kt=0;kt<4;kt++)
            wf[i][kt] = *(const bf16x8*)&WTb[(size_t)row*H_ + kt*32 + lq*8];
    }
    for(int g=0; g<4; g++){
        int node = nblk + g*16 + lm;
        bf16x8 hb[4];
        #pragma unroll
        for(int kt=0;kt<4;kt++)
            hb[kt] = *(const bf16x8*)&hb16[(size_t)node*H_ + kt*32 + lq*8];
        f32x4 acc[4];
        #pragma unroll
        for(int i=0;i<4;i++) acc[i] = (f32x4){0.f,0.f,0.f,0.f};
        #pragma unroll
        for(int kt=0;kt<4;kt++){
            #pragma unroll
            for(int i=0;i<4;i++)
                acc[i] = __builtin_amdgcn_mfma_f32_16x16x32_bf16(wf[i][kt], hb[kt], acc[i], 0,0,0);
        }
        #pragma unroll
        for(int i=0;i<4;i++){
            int col = (ct0+i)*16 + lq*4;
            ushort4 o;
            o.x=f2bf(acc[i][0]); o.y=f2bf(acc[i][1]); o.z=f2bf(acc[i][2]); o.w=f2bf(acc[i][3]);
            if(col < HC) *(ushort4*)&xl[(size_t)node*HC + col] = o;
            else         *(ushort4*)&xr[(size_t)node*HC + (col-HC)] = o;
        }
    }
}

// ---------------- edge src/dst helper ----------------
__device__ __forceinline__ void edge_sd(int e, const int* __restrict__ edges, int* src, int* dst){
    if(e < EG){
        int b = e / E_, j = e - b*E_;
        *src = edges[(b*2+0)*E_ + j] + b*N_;
        *dst = edges[(b*2+1)*E_ + j] + b*N_;
    } else { *src = *dst = e - EG; }
}

// ---------------- K4: GATv2 edge logits + fused segment-max ----------------
__global__ __launch_bounds__(256) void k_logits(const unsigned short* __restrict__ xl,
        const unsigned short* __restrict__ xr, const int* __restrict__ edges,
        const float* __restrict__ atta, float* __restrict__ logits,
        unsigned* __restrict__ segmax){
    __shared__ float sA[HEADS*H_];
    int t = threadIdx.x;
    for(int i=t;i<HEADS*H_;i+=256) sA[i]=atta[i];
    __syncthreads();
    int lane = t & 63;
    int e = blockIdx.x*4 + (t >> 6);
    if(e >= ETOT) return;
    int src, dst; edge_sd(e, edges, &src, &dst);
    const unsigned short* xls = &xl[(size_t)src*HC];
    const unsigned short* xrd = &xr[(size_t)dst*HC];
    for(int hh=0; hh<HEADS; hh++){
        float s1 = bf2f(xls[hh*H_+lane])    + bf2f(xrd[hh*H_+lane]);
        float s2 = bf2f(xls[hh*H_+lane+64]) + bf2f(xrd[hh*H_+lane+64]);
        s1 = s1 > 0.f ? s1 : NEG_SLOPE*s1;
        s2 = s2 > 0.f ? s2 : NEG_SLOPE*s2;
        float p = s1*sA[hh*H_+lane] + s2*sA[hh*H_+lane+64];
        #pragma unroll
        for(int off=32; off; off>>=1) p += __shfl_xor(p, off);
        if(lane==0){
            logits[(size_t)e*HEADS+hh] = p;
            unsigned u = __float_as_uint(p);
            u = (u & 0x80000000u) ? ~u : (u | 0x80000000u);
            atomicMax(&segmax[dst*HEADS+hh], u);
        }
    }
}

// ---------------- K5b: p = exp(logit - m), segsum += p ----------------
__global__ void k_expsum(float* __restrict__ pbuf, const int* __restrict__ edges,
                         const unsigned* __restrict__ segmax, float* __restrict__ segsum){
    int idx = blockIdx.x*256 + threadIdx.x;
    if(idx >= ETOT*HEADS) return;
    int e = idx / HEADS, hh = idx - e*HEADS;
    int src, dst; edge_sd(e, edges, &src, &dst);
    unsigned u = segmax[dst*HEADS+hh];
    float m = (u & 0x80000000u) ? __uint_as_float(u ^ 0x80000000u) : __uint_as_float(~u);
    float p = __expf(pbuf[idx] - m);
    pbuf[idx] = p;
    atomicAdd(&segsum[dst*HEADS+hh], p);
}

// ---------------- K5c: alpha out + sparse node_out accumulation ----------------
__global__ void k_alpha(const float* __restrict__ pbuf, const float* __restrict__ segsum,
                        const int* __restrict__ edges, const unsigned short* __restrict__ xl,
                        float* __restrict__ out_alpha, float* __restrict__ node_out){
    int idx = blockIdx.x*256 + threadIdx.x;
    if(idx >= ETOT*HEADS) return;
    int e = idx / HEADS, hh = idx - e*HEADS;
    int src, dst; edge_sd(e, edges, &src, &dst);
    float a = pbuf[idx] / segsum[dst*HEADS+hh];
    out_alpha[idx] = a;
    if(dst % N_ == 0){   // only ego nodes b*N feed the head
        int b = dst / N_;
        const unsigned short* x = &xl[(size_t)src*HC + hh*H_];
        float* no = &node_out[b*HC + hh*H_];
        for(int c=0;c<H_;c++) atomicAdd(&no[c], a * bf2f(x[c]));
    }
}

// ---------------- K6: conv1 4->32, 32x32 -> 16x16, stride2 SAME ----------------
__global__ __launch_bounds__(256) void k_conv1(const float* __restrict__ im,
        const float* __restrict__ w, const float* __restrict__ bias, float* __restrict__ outp){
    __shared__ float sW[32*4*9];
    int t = threadIdx.x;
    for(int i=t;i<32*4*9;i+=256) sW[i]=w[i];
    __syncthreads();
    int idx = blockIdx.x*256 + t;
    if(idx >= 16*32*16*16) return;
    int ox = idx & 15, oy = (idx>>4)&15, oc = (idx>>8)&31, b = idx>>13;
    float acc = bias[oc];
    for(int ic=0;ic<4;ic++){
        const float* ip = &im[(size_t)((b*4+ic)*32)*32];
        const float* wp = &sW[(oc*4+ic)*9];
        #pragma unroll
        for(int ky=0;ky<3;ky++){
            int iy = oy*2+ky; if(iy>=32) continue;
            #pragma unroll
            for(int kx=0;kx<3;kx++){
                int ix = ox*2+kx; if(ix>=32) continue;
                acc = fmaf(ip[iy*32+ix], wp[ky*3+kx], acc);
            }
        }
    }
    outp[idx] = fmaxf(acc, 0.f);
}

// ---------------- K7: conv2 32->64, 16x16 -> 8x8 ----------------
__global__ __launch_bounds__(256) void k_conv2(const float* __restrict__ c1,
        const float* __restrict__ w, const float* __restrict__ bias, float* __restrict__ outp){
    int idx = blockIdx.x*256 + threadIdx.x;
    if(idx >= 16*64*8*8) return;
    int ox = idx & 7, oy = (idx>>3)&7, oc = (idx>>6)&63, b = idx>>12;
    float acc = bias[oc];
    for(int ic=0;ic<32;ic++){
        const float* ip = &c1[(size_t)((b*32+ic)*16)*16];
        const float* wp = &w[(oc*32+ic)*9];
        #pragma unroll
        for(int ky=0;ky<3;ky++){
            int iy = oy*2+ky; if(iy>=16) continue;
            #pragma unroll
            for(int kx=0;kx<3;kx++){
                int ix = ox*2+kx; if(ix>=16) continue;
                acc = fmaf(ip[iy*16+ix], wp[ky*3+kx], acc);
            }
        }
    }
    outp[idx] = fmaxf(acc, 0.f);
}

// ---------------- K8: temb partial GEMM [16,4096]@[4096,128] via k-split atomics ------
__global__ void k_tembacc(const float* __restrict__ c2, const float* __restrict__ Wc,
                          float* __restrict__ tacc){
    int t = threadIdx.x;
    int b = blockIdx.x >> 3, ks = blockIdx.x & 7;
    int j = t & 127, sub = t >> 7;
    int k0 = ks*512 + sub*256;
    const float* cp = &c2[(size_t)b*4096];
    float acc = 0.f;
    for(int k=k0;k<k0+256;k++) acc = fmaf(cp[k], Wc[(size_t)k*H_+j], acc);
    atomicAdd(&tacc[b*H_+j], acc);
}

// ---------------- K9: head ----------------
__global__ __launch_bounds__(256) void k_head(const float* __restrict__ node_out,
        const float* __restrict__ gat_bias, const float* __restrict__ tacc,
        const float* __restrict__ bc, const float* __restrict__ phase,
        const float* __restrict__ Wp, const float* __restrict__ bp,
        const float* __restrict__ Wh, const float* __restrict__ bh,
        const float* __restrict__ Wo, const float* __restrict__ bo,
        const float* __restrict__ Wa, const float* __restrict__ ba,
        float* __restrict__ out){
    __shared__ float sF[16][268];
    __shared__ float sHid[16][132];
    int t = threadIdx.x;
    for(int i=t;i<B_*H_;i+=256){
        int b=i>>7, c=i&127;
        float s=0.f;
        #pragma unroll
        for(int hh=0;hh<HEADS;hh++) s += node_out[b*HC + hh*H_ + c];
        sF[b][c] = s*(1.0f/HEADS) + gat_bias[c];
    }
    for(int i=t;i<B_*H_;i+=256){
        int b=i>>7, c=i&127;
        sF[b][128+c] = fmaxf(tacc[i] + bc[c], 0.f);
    }
    if(t < B_*P_){
        int b=t>>3, p=t&7;
        float s=bp[p];
        #pragma unroll
        for(int q=0;q<P_;q++) s = fmaf(phase[b*P_+q], Wp[q*P_+p], s);
        sF[b][256+p] = fmaxf(s, 0.f);
    }
    __syncthreads();
    for(int i=t;i<B_*H_;i+=256){
        int b=i>>7, j=i&127;
        float s=bh[j];
        for(int k=0;k<2*H_+P_;k++) s = fmaf(sF[b][k], Wh[k*H_+j], s);
        sHid[b][j]=fmaxf(s,0.f);
    }
    __syncthreads();
    if(t < B_*A_){
        int b=t>>3, a=t&7;
        float v=bo[0], ad=ba[a];
        for(int k=0;k<H_;k++){ float hv=sHid[b][k]; v = fmaf(hv,Wo[k],v); ad = fmaf(hv,Wa[k*A_+a],ad); }
        float m = ad;
        m += __shfl_xor(m,1); m += __shfl_xor(m,2); m += __shfl_xor(m,4);
        m *= 0.125f;
        out[b*A_+a] = v + ad - m;
    }
}

extern "C" void kernel_launch(void* const* d_in, const int* in_sizes, int n_in,
                              void* d_out, int out_size, void* d_ws, size_t ws_size,
                              hipStream_t stream) {
    (void)in_sizes; (void)n_in; (void)out_size; (void)ws_size;
    const float* obs      = (const float*)d_in[0];
    const float* phase    = (const float*)d_in[1];
    const float* obs_map  = (const float*)d_in[2];
    const int*   edges    = (const int*)  d_in[3];
    const float* W_nbrs   = (const float*)d_in[5];
    const float* b_nbrs   = (const float*)d_in[6];
    const float* W_ih     = (const float*)d_in[7];
    const float* W_hh     = (const float*)d_in[8];
    const float* b_ih     = (const float*)d_in[9];
    const float* b_hh     = (const float*)d_in[10];
    const float* Wl       = (const float*)d_in[11];
    const float* Wr       = (const float*)d_in[12];
    const float* att_a    = (const float*)d_in[13];
    const float* gat_bias = (const float*)d_in[14];
    const float* conv1_w  = (const float*)d_in[15];
    const float* conv1_b  = (const float*)d_in[16];
    const float* conv2_w  = (const float*)d_in[17];
    const float* conv2_b  = (const float*)d_in[18];
    const float* Wc       = (const float*)d_in[19];
    const float* bc       = (const float*)d_in[20];
    const float* Wp       = (const float*)d_in[21];
    const float* bp       = (const float*)d_in[22];
    const float* Wh       = (const float*)d_in[23];
    const float* bh       = (const float*)d_in[24];
    const float* Wo       = (const float*)d_in[25];
    const float* bo       = (const float*)d_in[26];
    const float* Wa       = (const float*)d_in[27];
    const float* ba       = (const float*)d_in[28];

    float* out = (float*)d_out;                 // [0,128): out ; [128,400128): alpha
    float* w   = (float*)d_ws;

    // ws layout (float units)
    size_t off = 0;
    unsigned short* gx   = (unsigned short*)(w + off); off += (size_t)CN*T_*G3/2;
    unsigned short* hbuf = (unsigned short*)(w + off); off += (size_t)BN_*H_/2;
    unsigned short* xl   = (unsigned short*)(w + off); off += (size_t)BN_*HC/2;
    unsigned short* xr   = (unsigned short*)(w + off); off += (size_t)BN_*HC/2;
    float* pbuf   = w + off; off += (size_t)ETOT*HEADS;
    unsigned* segmax = (unsigned*)(w + off); off += (size_t)BN_*HEADS;
    float* segsum = w + off; off += (size_t)BN_*HEADS;
    float* nodeo  = w + off; off += (size_t)B_*HC;
    float* c1     = w + off; off += (size_t)16*32*16*16;
    float* c2     = w + off; off += (size_t)16*64*8*8;
    float* tacc   = w + off; off += (size_t)B_*H_;
    unsigned short* Wihb = (unsigned short*)(w + off); off += (size_t)H_*G3/2;
    unsigned short* Whhb = (unsigned short*)(w + off); off += (size_t)H_*G3/2;
    unsigned short* WTb  = (unsigned short*)(w + off); off += (size_t)2*HC*H_/2;

    k_prep<<<(2*HC*H_+255)/256, 256, 0, stream>>>(W_ih, W_hh, Wl, Wr, Wihb, Whhb, WTb);
    k_init<<<(BN_*HEADS+255)/256, 256, 0, stream>>>(segmax, segsum, nodeo, tacc);

    for(int c=0;c<CHUNKS;c++){
        k_gx <<<CN*T_/64, 256, 0, stream>>>(obs, W_nbrs, b_nbrs, Wihb, b_ih, gx, c*CN*T_);
        k_gru<<<CN/16,    256, 0, stream>>>(gx, Whhb, b_hh, hbuf, c*CN);
    }
    k_xlxr<<<dim3(BN_/64, 5), 256, 0, stream>>>(hbuf, WTb, xl, xr);
    k_logits<<<ETOT/4, 256, 0, stream>>>(xl, xr, edges, att_a, pbuf, segmax);
    k_expsum<<<(ETOT*HEADS+255)/256, 256, 0, stream>>>(pbuf, edges, segmax, segsum);
    k_alpha <<<(ETOT*HEADS+255)/256, 256, 0, stream>>>(pbuf, segsum, edges, xl, out+128, nodeo);
    k_conv1<<<(16*32*16*16)/256, 256, 0, stream>>>(obs_map, conv1_w, conv1_b, c1);
    k_conv2<<<(16*64*8*8)/256, 256, 0, stream>>>(c1, conv2_w, conv2_b, c2);
    k_tembacc<<<16*8, 256, 0, stream>>>(c2, Wc, tacc);
    k_head<<<1, 256, 0, stream>>>(nodeo, gat_bias, tacc, bc, phase,
                                  Wp, bp, Wh, bh, Wo, bo, Wa, ba, out);
}

// Round 4
// 412.867 us; speedup vs baseline: 3.8101x; 1.1385x over previous
//
#include <hip/hip_runtime.h>
#include <hip/hip_bf16.h>
#include <math.h>

#define B_    16
#define N_    1000
#define BN_   16000
#define T_    16
#define FO    16
#define H_    128
#define G3    384       // 3*H
#define HEADS 5
#define HC    640       // heads*H
#define E_    4000
#define EG    64000     // B*E
#define ETOT  80000     // EG + BN self loops
#define P_    8
#define A_    8
#define CHUNKS 2
#define CN    8000      // nodes per chunk
#define NEG_SLOPE 0.2f

typedef __attribute__((ext_vector_type(8))) short bf16x8;
typedef __attribute__((ext_vector_type(4))) float f32x4;

__device__ __forceinline__ float fsigmoid(float x){ return 1.0f/(1.0f + __expf(-x)); }
__device__ __forceinline__ float ftanh_(float x){ return 2.0f/(1.0f + __expf(-2.0f*x)) - 1.0f; }
__device__ __forceinline__ float bf2f(unsigned short u){ return __uint_as_float(((unsigned)u)<<16); }
__device__ __forceinline__ unsigned short f2bf(float x){
    unsigned u = __float_as_uint(x);
    unsigned r = (u + 0x7FFFu + ((u>>16)&1u)) >> 16;
    return (unsigned short)r;
}
__device__ __forceinline__ void f4a(float4 v, float* a){ a[0]=v.x; a[1]=v.y; a[2]=v.z; a[3]=v.w; }

// ---------------- K_prep: bf16 weight prep ----------------
// Wih/Whh f32 -> bf16 row-major [384][128]; WT[1280][128] = [Wl|Wr]^T bf16.
__global__ void k_prep(const float* __restrict__ Wih, const float* __restrict__ Whh,
                       const float* __restrict__ Wl, const float* __restrict__ Wr,
                       unsigned short* __restrict__ Wihb, unsigned short* __restrict__ Whhb,
                       unsigned short* __restrict__ WTb){
    int i = blockIdx.x*256 + threadIdx.x;
    if(i < G3*H_){ Wihb[i] = f2bf(Wih[i]); Whhb[i] = f2bf(Whh[i]); }
    if(i < 2*HC*H_){
        int c = i >> 7, k = i & 127;
        float v = (c < HC) ? Wl[(size_t)k*HC + c] : Wr[(size_t)k*HC + (c-HC)];
        WTb[i] = f2bf(v);
    }
}

// ---------------- K_init: zero/seed atomics buffers ----------------
__global__ void k_init(unsigned* __restrict__ segmax, float* __restrict__ segsum,
                       float* __restrict__ node_out, float* __restrict__ tacc){
    int i = blockIdx.x*256 + threadIdx.x;
    if(i < BN_*HEADS){ segmax[i] = 0x007FFFFFu; segsum[i] = 0.0f; } // encode(-inf)
    if(i < B_*HC)  node_out[i] = 0.0f;
    if(i < B_*H_)  tacc[i] = 0.0f;
}

// ============ K1: gx = relu(obs@Wn+bn)@WihT + bih, MFMA bf16 ============
__global__ __launch_bounds__(256,2) void k_gx(const float* __restrict__ obs,
        const float* __restrict__ Wn, const float* __restrict__ bn,
        const unsigned short* __restrict__ Wihb, const float* __restrict__ bih,
        unsigned short* __restrict__ gxout, int chunk_row_base){
    __shared__ float sObs[64][17];
    __shared__ float sWn[FO*H_];
    __shared__ unsigned short sX[64*128];   // bf16, 16B-chunk XOR-swizzled
    int t = threadIdx.x;
    int w = t>>6, lane = t&63, lq = lane>>4, lm = lane&15;
    const int tm[6] = {2*w, 2*w+1, 8+2*w, 8+2*w+1, 16+2*w, 16+2*w+1};

    bf16x8 wf[6][4];
    #pragma unroll
    for(int i=0;i<6;i++){
        int row = tm[i]*16 + lm;
        #pragma unroll
        for(int kt=0;kt<4;kt++)
            wf[i][kt] = *(const bf16x8*)&Wihb[row*H_ + kt*32 + lq*8];
    }
    float bias[6][4];
    #pragma unroll
    for(int i=0;i<6;i++){
        f32x4 bv = *(const f32x4*)&bih[tm[i]*16 + lq*4];
        #pragma unroll
        for(int v=0;v<4;v++) bias[i][v] = bv[v];
    }

    int rowBase = chunk_row_base + blockIdx.x*64;
    for(int i=t;i<64*16;i+=256) sObs[i>>4][i&15] = obs[(size_t)(rowBase+(i>>4))*FO + (i&15)];
    for(int i=t;i<FO*H_;i+=256) sWn[i] = Wn[i];
    __syncthreads();

    { // X = relu(obs@Wn+bn)
        int r = t&63, c0 = (t>>6)*32;
        float a[32];
        #pragma unroll
        for(int j=0;j<32;j++) a[j] = bn[c0+j];
        #pragma unroll
        for(int k=0;k<FO;k++){
            float ov = sObs[r][k];
            #pragma unroll
            for(int j=0;j<32;j++) a[j] = fmaf(ov, sWn[k*H_+c0+j], a[j]);
        }
        #pragma unroll
        for(int j4=0;j4<4;j4++){
            unsigned pk0 = (unsigned)f2bf(fmaxf(a[j4*8+0],0.f)) | ((unsigned)f2bf(fmaxf(a[j4*8+1],0.f))<<16);
            unsigned pk1 = (unsigned)f2bf(fmaxf(a[j4*8+2],0.f)) | ((unsigned)f2bf(fmaxf(a[j4*8+3],0.f))<<16);
            unsigned pk2 = (unsigned)f2bf(fmaxf(a[j4*8+4],0.f)) | ((unsigned)f2bf(fmaxf(a[j4*8+5],0.f))<<16);
            unsigned pk3 = (unsigned)f2bf(fmaxf(a[j4*8+6],0.f)) | ((unsigned)f2bf(fmaxf(a[j4*8+7],0.f))<<16);
            int chunk = ((c0>>3) + j4) ^ (r&7);
            *(uint4*)&sX[r*128 + chunk*8] = make_uint4(pk0,pk1,pk2,pk3);
        }
    }
    __syncthreads();

    for(int g=0; g<4; g++){
        bf16x8 xb[4];
        int row = g*16 + lm;
        #pragma unroll
        for(int kt=0;kt<4;kt++){
            int chunk = (4*kt + lq) ^ (row&7);
            xb[kt] = *(const bf16x8*)&sX[row*128 + chunk*8];
        }
        f32x4 acc[6];
        #pragma unroll
        for(int i=0;i<6;i++) acc[i] = (f32x4){0.f,0.f,0.f,0.f};
        #pragma unroll
        for(int kt=0;kt<4;kt++){
            #pragma unroll
            for(int i=0;i<6;i++)
                acc[i] = __builtin_amdgcn_mfma_f32_16x16x32_bf16(wf[i][kt], xb[kt], acc[i], 0,0,0);
        }
        size_t orow = (size_t)(blockIdx.x*64 + g*16 + lm)*G3;
        #pragma unroll
        for(int i=0;i<6;i++){
            ushort4 o;
            o.x = f2bf(acc[i][0] + bias[i][0]);
            o.y = f2bf(acc[i][1] + bias[i][1]);
            o.z = f2bf(acc[i][2] + bias[i][2]);
            o.w = f2bf(acc[i][3] + bias[i][3]);
            *(ushort4*)&gxout[orow + tm[i]*16 + lq*4] = o;
        }
    }
}

// ============ K2: GRU recurrence, MFMA bf16. h output bf16 ============
__global__ __launch_bounds__(256,2) void k_gru(const unsigned short* __restrict__ gx,
        const unsigned short* __restrict__ Whhb, const float* __restrict__ bhh,
        unsigned short* __restrict__ hout, int chunk_node_base){
    __shared__ unsigned short sH[2][16*128];   // bf16, double-buffered, swizzled
    int t = threadIdx.x;
    int w = t>>6, lane = t&63, lq = lane>>4, lm = lane&15;
    const int tm[6] = {2*w, 2*w+1, 8+2*w, 8+2*w+1, 16+2*w, 16+2*w+1};

    bf16x8 wf[6][4];
    #pragma unroll
    for(int i=0;i<6;i++){
        int row = tm[i]*16 + lm;
        #pragma unroll
        for(int kt=0;kt<4;kt++)
            wf[i][kt] = *(const bf16x8*)&Whhb[row*H_ + kt*32 + lq*8];
    }
    float bias[6][4];
    #pragma unroll
    for(int i=0;i<6;i++){
        f32x4 bv = *(const f32x4*)&bhh[tm[i]*16 + lq*4];
        #pragma unroll
        for(int v=0;v<4;v++) bias[i][v] = bv[v];
    }

    for(int i=t;i<1024;i+=256) ((unsigned*)sH)[i] = 0;
    float ho[2][4] = {{0.f,0.f,0.f,0.f},{0.f,0.f,0.f,0.f}};
    __syncthreads();

    int nodeBase = blockIdx.x*16;   // chunk-local
    const unsigned short* gxrow0 = &gx[(size_t)(nodeBase + lm)*T_*G3];
    int colb = 32*w + lq*4;
    int p = 0;
    for(int step=0; step<T_; step++){
        const unsigned short* gr = gxrow0 + (size_t)step*G3;
        ushort4 xr[2], xz[2], xn[2];
        xr[0] = *(const ushort4*)&gr[colb];       xr[1] = *(const ushort4*)&gr[colb+16];
        xz[0] = *(const ushort4*)&gr[colb+128];   xz[1] = *(const ushort4*)&gr[colb+144];
        xn[0] = *(const ushort4*)&gr[colb+256];   xn[1] = *(const ushort4*)&gr[colb+272];
        bf16x8 hb[4];
        #pragma unroll
        for(int kt=0;kt<4;kt++){
            int chunk = (4*kt + lq) ^ (lm&7);
            hb[kt] = *(const bf16x8*)&sH[p][lm*128 + chunk*8];
        }
        f32x4 acc[6];
        #pragma unroll
        for(int i=0;i<6;i++) acc[i] = (f32x4){0.f,0.f,0.f,0.f};
        #pragma unroll
        for(int kt=0;kt<4;kt++){
            #pragma unroll
            for(int i=0;i<6;i++)
                acc[i] = __builtin_amdgcn_mfma_f32_16x16x32_bf16(wf[i][kt], hb[kt], acc[i], 0,0,0);
        }
        #pragma unroll
        for(int u=0;u<2;u++){
            unsigned short hwa[4];
            unsigned short xra[4]={xr[u].x,xr[u].y,xr[u].z,xr[u].w};
            unsigned short xza[4]={xz[u].x,xz[u].y,xz[u].z,xz[u].w};
            unsigned short xna[4]={xn[u].x,xn[u].y,xn[u].z,xn[u].w};
            #pragma unroll
            for(int v=0;v<4;v++){
                float hr = acc[0+u][v] + bias[0+u][v];
                float hz = acc[2+u][v] + bias[2+u][v];
                float hn = acc[4+u][v] + bias[4+u][v];
                float r  = fsigmoid(bf2f(xra[v]) + hr);
                float z  = fsigmoid(bf2f(xza[v]) + hz);
                float nn = ftanh_(bf2f(xna[v]) + r*hn);
                float hv = (1.f - z)*nn + z*ho[u][v];
                ho[u][v] = hv;
                hwa[v] = f2bf(hv);
            }
            int chunk = (4*w + 2*u + (lq>>1)) ^ (lm&7);
            int half = lq & 1;
            *(uint2*)&sH[p^1][lm*128 + chunk*8 + half*4] =
                make_uint2((unsigned)hwa[0] | ((unsigned)hwa[1]<<16),
                           (unsigned)hwa[2] | ((unsigned)hwa[3]<<16));
        }
        __syncthreads();
        p ^= 1;
    }
    int node = chunk_node_base + nodeBase + lm;
    #pragma unroll
    for(int u=0;u<2;u++){
        ushort4 o;
        o.x=f2bf(ho[u][0]); o.y=f2bf(ho[u][1]); o.z=f2bf(ho[u][2]); o.w=f2bf(ho[u][3]);
        *(ushort4*)&hout[(size_t)node*H_ + 32*w + 16*u + lq*4] = o;
    }
}

// ============ K3: xl|xr = h @ [Wl|Wr], MFMA bf16, no LDS ============
__global__ __launch_bounds__(256) void k_xlxr(const unsigned short* __restrict__ hb16,
        const unsigned short* __restrict__ WTb,
        unsigned short* __restrict__ xl, unsigned short* __restrict__ xr){
    int t = threadIdx.x;
    int w = t>>6, lane = t&63, lq = lane>>4, lm = lane&15;
    int nblk = blockIdx.x*64;
    int ct0 = blockIdx.y*16 + w*4;          // first col tile of this wave

    bf16x8 wf[4][4];
    #pragma unroll
    for(int i=0;i<4;i++){
        int row = (ct0+i)*16 + lm;          // out col
        #pragma unroll
        for(int kt=0;kt<4;kt++)
            wf[i][kt] = *(const bf16x8*)&WTb[(size_t)row*H_ + kt*32 + lq*8];
    }
    for(int g=0; g<4; g++){
        int node = nblk + g*16 + lm;
        bf16x8 hb[4];
        #pragma unroll
        for(int kt=0;kt<4;kt++)
            hb[kt] = *(const bf16x8*)&hb16[(size_t)node*H_ + kt*32 + lq*8];
        f32x4 acc[4];
        #pragma unroll
        for(int i=0;i<4;i++) acc[i] = (f32x4){0.f,0.f,0.f,0.f};
        #pragma unroll
        for(int kt=0;kt<4;kt++){
            #pragma unroll
            for(int i=0;i<4;i++)
                acc[i] = __builtin_amdgcn_mfma_f32_16x16x32_bf16(wf[i][kt], hb[kt], acc[i], 0,0,0);
        }
        #pragma unroll
        for(int i=0;i<4;i++){
            int col = (ct0+i)*16 + lq*4;
            ushort4 o;
            o.x=f2bf(acc[i][0]); o.y=f2bf(acc[i][1]); o.z=f2bf(acc[i][2]); o.w=f2bf(acc[i][3]);
            if(col < HC) *(ushort4*)&xl[(size_t)node*HC + col] = o;
            else         *(ushort4*)&xr[(size_t)node*HC + (col-HC)] = o;
        }
    }
}

// ---------------- edge src/dst helper ----------------
__device__ __forceinline__ void edge_sd(int e, const int* __restrict__ edges, int* src, int* dst){
    if(e < EG){
        int b = e / E_, j = e - b*E_;
        *src = edges[(b*2+0)*E_ + j] + b*N_;
        *dst = edges[(b*2+1)*E_ + j] + b*N_;
    } else { *src = *dst = e - EG; }
}

// ---------------- K4: GATv2 edge logits + fused segment-max ----------------
__global__ __launch_bounds__(256) void k_logits(const unsigned short* __restrict__ xl,
        const unsigned short* __restrict__ xr, const int* __restrict__ edges,
        const float* __restrict__ atta, float* __restrict__ logits,
        unsigned* __restrict__ segmax){
    __shared__ float sA[HEADS*H_];
    int t = threadIdx.x;
    for(int i=t;i<HEADS*H_;i+=256) sA[i]=atta[i];
    __syncthreads();
    int lane = t & 63;
    int e = blockIdx.x*4 + (t >> 6);
    if(e >= ETOT) return;
    int src, dst; edge_sd(e, edges, &src, &dst);
    const unsigned short* xls = &xl[(size_t)src*HC];
    const unsigned short* xrd = &xr[(size_t)dst*HC];
    for(int hh=0; hh<HEADS; hh++){
        float s1 = bf2f(xls[hh*H_+lane])    + bf2f(xrd[hh*H_+lane]);
        float s2 = bf2f(xls[hh*H_+lane+64]) + bf2f(xrd[hh*H_+lane+64]);
        s1 = s1 > 0.f ? s1 : NEG_SLOPE*s1;
        s2 = s2 > 0.f ? s2 : NEG_SLOPE*s2;
        float p = s1*sA[hh*H_+lane] + s2*sA[hh*H_+lane+64];
        #pragma unroll
        for(int off=32; off; off>>=1) p += __shfl_xor(p, off);
        if(lane==0){
            logits[(size_t)e*HEADS+hh] = p;
            unsigned u = __float_as_uint(p);
            u = (u & 0x80000000u) ? ~u : (u | 0x80000000u);
            atomicMax(&segmax[dst*HEADS+hh], u);
        }
    }
}

// ---------------- K5b: p = exp(logit - m), segsum += p ----------------
__global__ void k_expsum(float* __restrict__ pbuf, const int* __restrict__ edges,
                         const unsigned* __restrict__ segmax, float* __restrict__ segsum){
    int idx = blockIdx.x*256 + threadIdx.x;
    if(idx >= ETOT*HEADS) return;
    int e = idx / HEADS, hh = idx - e*HEADS;
    int src, dst; edge_sd(e, edges, &src, &dst);
    unsigned u = segmax[dst*HEADS+hh];
    float m = (u & 0x80000000u) ? __uint_as_float(u ^ 0x80000000u) : __uint_as_float(~u);
    float p = __expf(pbuf[idx] - m);
    pbuf[idx] = p;
    atomicAdd(&segsum[dst*HEADS+hh], p);
}

// ---------------- K5c: alpha out + sparse node_out accumulation ----------------
__global__ void k_alpha(const float* __restrict__ pbuf, const float* __restrict__ segsum,
                        const int* __restrict__ edges, const unsigned short* __restrict__ xl,
                        float* __restrict__ out_alpha, float* __restrict__ node_out){
    int idx = blockIdx.x*256 + threadIdx.x;
    if(idx >= ETOT*HEADS) return;
    int e = idx / HEADS, hh = idx - e*HEADS;
    int src, dst; edge_sd(e, edges, &src, &dst);
    float a = pbuf[idx] / segsum[dst*HEADS+hh];
    out_alpha[idx] = a;
    if(dst % N_ == 0){   // only ego nodes b*N feed the head
        int b = dst / N_;
        const unsigned short* x = &xl[(size_t)src*HC + hh*H_];
        float* no = &node_out[b*HC + hh*H_];
        for(int c=0;c<H_;c++) atomicAdd(&no[c], a * bf2f(x[c]));
    }
}

// ---------------- K6: conv1 4->32, 32x32 -> 16x16, stride2 SAME ----------------
__global__ __launch_bounds__(256) void k_conv1(const float* __restrict__ im,
        const float* __restrict__ w, const float* __restrict__ bias, float* __restrict__ outp){
    __shared__ float sW[32*4*9];
    int t = threadIdx.x;
    for(int i=t;i<32*4*9;i+=256) sW[i]=w[i];
    __syncthreads();
    int idx = blockIdx.x*256 + t;
    if(idx >= 16*32*16*16) return;
    int ox = idx & 15, oy = (idx>>4)&15, oc = (idx>>8)&31, b = idx>>13;
    float acc = bias[oc];
    for(int ic=0;ic<4;ic++){
        const float* ip = &im[(size_t)((b*4+ic)*32)*32];
        const float* wp = &sW[(oc*4+ic)*9];
        #pragma unroll
        for(int ky=0;ky<3;ky++){
            int iy = oy*2+ky; if(iy>=32) continue;
            #pragma unroll
            for(int kx=0;kx<3;kx++){
                int ix = ox*2+kx; if(ix>=32) continue;
                acc = fmaf(ip[iy*32+ix], wp[ky*3+kx], acc);
            }
        }
    }
    outp[idx] = fmaxf(acc, 0.f);
}

// ---------------- K7: conv2 32->64, 16x16 -> 8x8 ----------------
__global__ __launch_bounds__(256) void k_conv2(const float* __restrict__ c1,
        const float* __restrict__ w, const float* __restrict__ bias, float* __restrict__ outp){
    int idx = blockIdx.x*256 + threadIdx.x;
    if(idx >= 16*64*8*8) return;
    int ox = idx & 7, oy = (idx>>3)&7, oc = (idx>>6)&63, b = idx>>12;
    float acc = bias[oc];
    for(int ic=0;ic<32;ic++){
        const float* ip = &c1[(size_t)((b*32+ic)*16)*16];
        const float* wp = &w[(oc*32+ic)*9];
        #pragma unroll
        for(int ky=0;ky<3;ky++){
            int iy = oy*2+ky; if(iy>=16) continue;
            #pragma unroll
            for(int kx=0;kx<3;kx++){
                int ix = ox*2+kx; if(ix>=16) continue;
                acc = fmaf(ip[iy*16+ix], wp[ky*3+kx], acc);
            }
        }
    }
    outp[idx] = fmaxf(acc, 0.f);
}

// ---------------- K8: temb partial GEMM, ILP-restructured ----------------
// grid 16 b x 32 kslices; block stages 128-float c2 slice in LDS; thread:
// j = t&127, sub = t>>7 -> 64 k each, 4 independent acc chains, full unroll.
__global__ __launch_bounds__(256) void k_tembacc(const float* __restrict__ c2,
        const float* __restrict__ Wc, float* __restrict__ tacc){
    __shared__ float sC[128];
    int t = threadIdx.x;
    int b = blockIdx.x >> 5, ks = blockIdx.x & 31;
    int k0 = ks*128;
    if(t < 128) sC[t] = c2[(size_t)b*4096 + k0 + t];
    __syncthreads();
    int j = t & 127, sub = t >> 7;
    const float* wp = &Wc[(size_t)(k0 + sub*64)*H_ + j];
    const float* cp = &sC[sub*64];
    float a0=0.f, a1=0.f, a2=0.f, a3=0.f;
    #pragma unroll
    for(int kk=0; kk<64; kk+=4){
        a0 = fmaf(cp[kk+0], wp[(size_t)(kk+0)*H_], a0);
        a1 = fmaf(cp[kk+1], wp[(size_t)(kk+1)*H_], a1);
        a2 = fmaf(cp[kk+2], wp[(size_t)(kk+2)*H_], a2);
        a3 = fmaf(cp[kk+3], wp[(size_t)(kk+3)*H_], a3);
    }
    atomicAdd(&tacc[b*H_+j], (a0+a1)+(a2+a3));
}

// ---------------- K9: head ----------------
__global__ __launch_bounds__(256) void k_head(const float* __restrict__ node_out,
        const float* __restrict__ gat_bias, const float* __restrict__ tacc,
        const float* __restrict__ bc, const float* __restrict__ phase,
        const float* __restrict__ Wp, const float* __restrict__ bp,
        const float* __restrict__ Wh, const float* __restrict__ bh,
        const float* __restrict__ Wo, const float* __restrict__ bo,
        const float* __restrict__ Wa, const float* __restrict__ ba,
        float* __restrict__ out){
    __shared__ float sF[16][268];
    __shared__ float sHid[16][132];
    int t = threadIdx.x;
    for(int i=t;i<B_*H_;i+=256){
        int b=i>>7, c=i&127;
        float s=0.f;
        #pragma unroll
        for(int hh=0;hh<HEADS;hh++) s += node_out[b*HC + hh*H_ + c];
        sF[b][c] = s*(1.0f/HEADS) + gat_bias[c];
    }
    for(int i=t;i<B_*H_;i+=256){
        int b=i>>7, c=i&127;
        sF[b][128+c] = fmaxf(tacc[i] + bc[c], 0.f);
    }
    if(t < B_*P_){
        int b=t>>3, p=t&7;
        float s=bp[p];
        #pragma unroll
        for(int q=0;q<P_;q++) s = fmaf(phase[b*P_+q], Wp[q*P_+p], s);
        sF[b][256+p] = fmaxf(s, 0.f);
    }
    __syncthreads();
    for(int i=t;i<B_*H_;i+=256){
        int b=i>>7, j=i&127;
        float s=bh[j];
        for(int k=0;k<2*H_+P_;k++) s = fmaf(sF[b][k], Wh[k*H_+j], s);
        sHid[b][j]=fmaxf(s,0.f);
    }
    __syncthreads();
    if(t < B_*A_){
        int b=t>>3, a=t&7;
        float v=bo[0], ad=ba[a];
        for(int k=0;k<H_;k++){ float hv=sHid[b][k]; v = fmaf(hv,Wo[k],v); ad = fmaf(hv,Wa[k*A_+a],ad); }
        float m = ad;
        m += __shfl_xor(m,1); m += __shfl_xor(m,2); m += __shfl_xor(m,4);
        m *= 0.125f;
        out[b*A_+a] = v + ad - m;
    }
}

extern "C" void kernel_launch(void* const* d_in, const int* in_sizes, int n_in,
                              void* d_out, int out_size, void* d_ws, size_t ws_size,
                              hipStream_t stream) {
    (void)in_sizes; (void)n_in; (void)out_size; (void)ws_size;
    const float* obs      = (const float*)d_in[0];
    const float* phase    = (const float*)d_in[1];
    const float* obs_map  = (const float*)d_in[2];
    const int*   edges    = (const int*)  d_in[3];
    const float* W_nbrs   = (const float*)d_in[5];
    const float* b_nbrs   = (const float*)d_in[6];
    const float* W_ih     = (const float*)d_in[7];
    const float* W_hh     = (const float*)d_in[8];
    const float* b_ih     = (const float*)d_in[9];
    const float* b_hh     = (const float*)d_in[10];
    const float* Wl       = (const float*)d_in[11];
    const float* Wr       = (const float*)d_in[12];
    const float* att_a    = (const float*)d_in[13];
    const float* gat_bias = (const float*)d_in[14];
    const float* conv1_w  = (const float*)d_in[15];
    const float* conv1_b  = (const float*)d_in[16];
    const float* conv2_w  = (const float*)d_in[17];
    const float* conv2_b  = (const float*)d_in[18];
    const float* Wc       = (const float*)d_in[19];
    const float* bc       = (const float*)d_in[20];
    const float* Wp       = (const float*)d_in[21];
    const float* bp       = (const float*)d_in[22];
    const float* Wh       = (const float*)d_in[23];
    const float* bh       = (const float*)d_in[24];
    const float* Wo       = (const float*)d_in[25];
    const float* bo       = (const float*)d_in[26];
    const float* Wa       = (const float*)d_in[27];
    const float* ba       = (const float*)d_in[28];

    float* out = (float*)d_out;                 // [0,128): out ; [128,400128): alpha
    float* w   = (float*)d_ws;

    // ws layout (float units)
    size_t off = 0;
    unsigned short* gx   = (unsigned short*)(w + off); off += (size_t)CN*T_*G3/2;
    unsigned short* hbuf = (unsigned short*)(w + off); off += (size_t)BN_*H_/2;
    unsigned short* xl   = (unsigned short*)(w + off); off += (size_t)BN_*HC/2;
    unsigned short* xr   = (unsigned short*)(w + off); off += (size_t)BN_*HC/2;
    float* pbuf   = w + off; off += (size_t)ETOT*HEADS;
    unsigned* segmax = (unsigned*)(w + off); off += (size_t)BN_*HEADS;
    float* segsum = w + off; off += (size_t)BN_*HEADS;
    float* nodeo  = w + off; off += (size_t)B_*HC;
    float* c1     = w + off; off += (size_t)16*32*16*16;
    float* c2     = w + off; off += (size_t)16*64*8*8;
    float* tacc   = w + off; off += (size_t)B_*H_;
    unsigned short* Wihb = (unsigned short*)(w + off); off += (size_t)H_*G3/2;
    unsigned short* Whhb = (unsigned short*)(w + off); off += (size_t)H_*G3/2;
    unsigned short* WTb  = (unsigned short*)(w + off); off += (size_t)2*HC*H_/2;

    k_prep<<<(2*HC*H_+255)/256, 256, 0, stream>>>(W_ih, W_hh, Wl, Wr, Wihb, Whhb, WTb);
    k_init<<<(BN_*HEADS+255)/256, 256, 0, stream>>>(segmax, segsum, nodeo, tacc);

    for(int c=0;c<CHUNKS;c++){
        k_gx <<<CN*T_/64, 256, 0, stream>>>(obs, W_nbrs, b_nbrs, Wihb, b_ih, gx, c*CN*T_);
        k_gru<<<CN/16,    256, 0, stream>>>(gx, Whhb, b_hh, hbuf, c*CN);
    }
    k_xlxr<<<dim3(BN_/64, 5), 256, 0, stream>>>(hbuf, WTb, xl, xr);
    k_logits<<<ETOT/4, 256, 0, stream>>>(xl, xr, edges, att_a, pbuf, segmax);
    k_expsum<<<(ETOT*HEADS+255)/256, 256, 0, stream>>>(pbuf, edges, segmax, segsum);
    k_alpha <<<(ETOT*HEADS+255)/256, 256, 0, stream>>>(pbuf, segsum, edges, xl, out+128, nodeo);
    k_conv1<<<(16*32*16*16)/256, 256, 0, stream>>>(obs_map, conv1_w, conv1_b, c1);
    k_conv2<<<(16*64*8*8)/256, 256, 0, stream>>>(c1, conv2_w, conv2_b, c2);
    k_tembacc<<<16*32, 256, 0, stream>>>(c2, Wc, tacc);
    k_head<<<1, 256, 0, stream>>>(nodeo, gat_bias, tacc, bc, phase,
                                  Wp, bp, Wh, bh, Wo, bo, Wa, ba, out);
}

// Round 5
// 302.037 us; speedup vs baseline: 5.2082x; 1.3669x over previous
//
#include <hip/hip_runtime.h>
#include <hip/hip_bf16.h>
#include <math.h>

#define B_    16
#define N_    1000
#define BN_   16000
#define T_    16
#define FO    16
#define H_    128
#define G3    384       // 3*H
#define HEADS 5
#define HC    640       // heads*H
#define E_    4000
#define EG    64000     // B*E
#define ETOT  80000     // EG + BN self loops
#define P_    8
#define A_    8
#define NEG_SLOPE 0.2f

typedef __attribute__((ext_vector_type(8))) short bf16x8;
typedef __attribute__((ext_vector_type(4))) float f32x4;

__device__ __forceinline__ float fsigmoid(float x){ return 1.0f/(1.0f + __expf(-x)); }
__device__ __forceinline__ float ftanh_(float x){ return 2.0f/(1.0f + __expf(-2.0f*x)) - 1.0f; }
__device__ __forceinline__ float bf2f(unsigned short u){ return __uint_as_float(((unsigned)u)<<16); }
__device__ __forceinline__ unsigned short f2bf(float x){
    unsigned u = __float_as_uint(x);
    unsigned r = (u + 0x7FFFu + ((u>>16)&1u)) >> 16;
    return (unsigned short)r;
}

// ---------------- K_prep: bf16 weight prep ----------------
// Wih/Whh -> bf16 [384][128]; WT[1280][128] = [Wl|Wr]^T; WnT[128][32] = Wn^T K-padded.
__global__ void k_prep(const float* __restrict__ Wih, const float* __restrict__ Whh,
                       const float* __restrict__ Wl, const float* __restrict__ Wr,
                       const float* __restrict__ Wn,
                       unsigned short* __restrict__ Wihb, unsigned short* __restrict__ Whhb,
                       unsigned short* __restrict__ WTb, unsigned short* __restrict__ WnTb){
    int i = blockIdx.x*256 + threadIdx.x;
    if(i < G3*H_){ Wihb[i] = f2bf(Wih[i]); Whhb[i] = f2bf(Whh[i]); }
    if(i < 2*HC*H_){
        int c = i >> 7, k = i & 127;
        float v = (c < HC) ? Wl[(size_t)k*HC + c] : Wr[(size_t)k*HC + (c-HC)];
        WTb[i] = f2bf(v);
    }
    if(i < H_*32){
        int c = i >> 5, k = i & 31;
        WnTb[i] = (k < FO) ? f2bf(Wn[k*H_ + c]) : (unsigned short)0;
    }
}

// ---------------- K_init: zero/seed atomics buffers ----------------
__global__ void k_init(unsigned* __restrict__ segmax, float* __restrict__ segsum,
                       float* __restrict__ node_out, float* __restrict__ tacc){
    int i = blockIdx.x*256 + threadIdx.x;
    if(i < BN_*HEADS){ segmax[i] = 0x007FFFFFu; segsum[i] = 0.0f; } // encode(-inf)
    if(i < B_*HC)  node_out[i] = 0.0f;
    if(i < B_*H_)  tacc[i] = 0.0f;
}

// ============ K_GRUF: fully fused obs-MLP + gx-GEMM + GRU recurrence ============
// 16 nodes/block, 8 waves (512 thr). Wave w owns gate cols [16w,16w+16):
// tiles r=w, z=8+w, n=16+w. gx never touches memory; X via one MFMA (Wn^T K-padded).
// MFMA output layout (lane=node lm, col=w*16+lq*4+v) IS the gate input layout.
__global__ __launch_bounds__(512,1) void k_gruf(const float* __restrict__ obs,
        const unsigned short* __restrict__ WnTb, const float* __restrict__ bn,
        const unsigned short* __restrict__ Wihb, const float* __restrict__ bih,
        const unsigned short* __restrict__ Whhb, const float* __restrict__ bhh,
        unsigned short* __restrict__ hout){
    __shared__ unsigned short sObs[16*264];       // bf16, +8 pad per row
    __shared__ unsigned short sX[16*128];         // bf16, XOR-swizzled
    __shared__ unsigned short sH[2][16*128];      // bf16, double-buffered, swizzled
    int t = threadIdx.x;
    int w = t>>6, lane = t&63, lq = lane>>4, lm = lane&15;

    // persistent weight fragments: 3 tiles ih + 3 tiles hh (96 VGPR)
    bf16x8 wfi[3][4], wfh[3][4];
    #pragma unroll
    for(int i=0;i<3;i++){
        int row = (8*i + w)*16 + lm;
        #pragma unroll
        for(int kt=0;kt<4;kt++){
            wfi[i][kt] = *(const bf16x8*)&Wihb[row*H_ + kt*32 + lq*8];
            wfh[i][kt] = *(const bf16x8*)&Whhb[row*H_ + kt*32 + lq*8];
        }
    }
    bf16x8 wfn = *(const bf16x8*)&WnTb[(w*16+lm)*32 + lq*8];
    int cb = w*16 + lq*4;                      // this lane's gate col base
    f32x4 bnv = *(const f32x4*)&bn[cb];
    f32x4 b_r, b_z, bxn, bhn;
    { f32x4 t1=*(const f32x4*)&bih[cb],     t2=*(const f32x4*)&bhh[cb];     b_r=t1+t2; }
    { f32x4 t1=*(const f32x4*)&bih[128+cb], t2=*(const f32x4*)&bhh[128+cb]; b_z=t1+t2; }
    bxn = *(const f32x4*)&bih[256+cb];
    bhn = *(const f32x4*)&bhh[256+cb];

    int nodeBase = blockIdx.x*16;
    for(int i=t; i<16*256; i+=512){
        int n = i>>8, j = i&255;
        sObs[n*264+j] = f2bf(obs[(size_t)(nodeBase+n)*256 + j]);
    }
    for(int i=t;i<2048;i+=512) ((unsigned*)sH)[i] = 0;
    float ho[4] = {0.f,0.f,0.f,0.f};
    __syncthreads();

    int wch = (2*w + (lq>>1)) ^ (lm&7);        // swizzled chunk for this lane's col-quad
    int p = 0;
    for(int step=0; step<T_; step++){
        // ---- phase 1: X = relu(obs @ Wn + bn) via MFMA (K padded 16->32) ----
        bf16x8 ob = (bf16x8){0,0,0,0,0,0,0,0};
        if(lq < 2) ob = *(const bf16x8*)&sObs[lm*264 + step*16 + lq*8];
        f32x4 xa = (f32x4){0.f,0.f,0.f,0.f};
        xa = __builtin_amdgcn_mfma_f32_16x16x32_bf16(wfn, ob, xa, 0,0,0);
        unsigned pk0, pk1;
        {
            float x0 = fmaxf(xa[0]+bnv[0],0.f), x1 = fmaxf(xa[1]+bnv[1],0.f);
            float x2 = fmaxf(xa[2]+bnv[2],0.f), x3 = fmaxf(xa[3]+bnv[3],0.f);
            pk0 = (unsigned)f2bf(x0) | ((unsigned)f2bf(x1)<<16);
            pk1 = (unsigned)f2bf(x2) | ((unsigned)f2bf(x3)<<16);
        }
        *(uint2*)&sX[lm*128 + wch*8 + (lq&1)*4] = make_uint2(pk0,pk1);
        __syncthreads();
        // ---- phase 2: gx-part + gh-part MFMAs (6 round-robin acc chains) ----
        bf16x8 xb[4], hb[4];
        #pragma unroll
        for(int kt=0;kt<4;kt++){
            int ch = (4*kt+lq) ^ (lm&7);
            xb[kt] = *(const bf16x8*)&sX[lm*128 + ch*8];
            hb[kt] = *(const bf16x8*)&sH[p][lm*128 + ch*8];
        }
        f32x4 ari={0,0,0,0}, azi={0,0,0,0}, axi={0,0,0,0};
        f32x4 arh={0,0,0,0}, azh={0,0,0,0}, ahh={0,0,0,0};
        #pragma unroll
        for(int kt=0;kt<4;kt++){
            ari = __builtin_amdgcn_mfma_f32_16x16x32_bf16(wfi[0][kt], xb[kt], ari, 0,0,0);
            azi = __builtin_amdgcn_mfma_f32_16x16x32_bf16(wfi[1][kt], xb[kt], azi, 0,0,0);
            axi = __builtin_amdgcn_mfma_f32_16x16x32_bf16(wfi[2][kt], xb[kt], axi, 0,0,0);
            arh = __builtin_amdgcn_mfma_f32_16x16x32_bf16(wfh[0][kt], hb[kt], arh, 0,0,0);
            azh = __builtin_amdgcn_mfma_f32_16x16x32_bf16(wfh[1][kt], hb[kt], azh, 0,0,0);
            ahh = __builtin_amdgcn_mfma_f32_16x16x32_bf16(wfh[2][kt], hb[kt], ahh, 0,0,0);
        }
        // ---- gates ----
        unsigned short hwa[4];
        #pragma unroll
        for(int v=0;v<4;v++){
            float r  = fsigmoid(ari[v] + arh[v] + b_r[v]);
            float z  = fsigmoid(azi[v] + azh[v] + b_z[v]);
            float nn = ftanh_(axi[v] + bxn[v] + r*(ahh[v] + bhn[v]));
            float hv = (1.f - z)*nn + z*ho[v];
            ho[v] = hv;
            hwa[v] = f2bf(hv);
        }
        *(uint2*)&sH[p^1][lm*128 + wch*8 + (lq&1)*4] =
            make_uint2((unsigned)hwa[0] | ((unsigned)hwa[1]<<16),
                       (unsigned)hwa[2] | ((unsigned)hwa[3]<<16));
        __syncthreads();
        p ^= 1;
    }
    ushort4 o;
    o.x=f2bf(ho[0]); o.y=f2bf(ho[1]); o.z=f2bf(ho[2]); o.w=f2bf(ho[3]);
    *(ushort4*)&hout[(size_t)(nodeBase+lm)*H_ + cb] = o;
}

// ============ K3: xl|xr = h @ [Wl|Wr], MFMA bf16, no LDS ============
__global__ __launch_bounds__(256) void k_xlxr(const unsigned short* __restrict__ hb16,
        const unsigned short* __restrict__ WTb,
        unsigned short* __restrict__ xl, unsigned short* __restrict__ xr){
    int t = threadIdx.x;
    int w = t>>6, lane = t&63, lq = lane>>4, lm = lane&15;
    int nblk = blockIdx.x*64;
    int ct0 = blockIdx.y*16 + w*4;          // first col tile of this wave

    bf16x8 wf[4][4];
    #pragma unroll
    for(int i=0;i<4;i++){
        int row = (ct0+i)*16 + lm;          // out col
        #pragma unroll
        for(int kt=0;kt<4;kt++)
            wf[i][kt] = *(const bf16x8*)&WTb[(size_t)row*H_ + kt*32 + lq*8];
    }
    for(int g=0; g<4; g++){
        int node = nblk + g*16 + lm;
        bf16x8 hb[4];
        #pragma unroll
        for(int kt=0;kt<4;kt++)
            hb[kt] = *(const bf16x8*)&hb16[(size_t)node*H_ + kt*32 + lq*8];
        f32x4 acc[4];
        #pragma unroll
        for(int i=0;i<4;i++) acc[i] = (f32x4){0.f,0.f,0.f,0.f};
        #pragma unroll
        for(int kt=0;kt<4;kt++){
            #pragma unroll
            for(int i=0;i<4;i++)
                acc[i] = __builtin_amdgcn_mfma_f32_16x16x32_bf16(wf[i][kt], hb[kt], acc[i], 0,0,0);
        }
        #pragma unroll
        for(int i=0;i<4;i++){
            int col = (ct0+i)*16 + lq*4;
            ushort4 o;
            o.x=f2bf(acc[i][0]); o.y=f2bf(acc[i][1]); o.z=f2bf(acc[i][2]); o.w=f2bf(acc[i][3]);
            if(col < HC) *(ushort4*)&xl[(size_t)node*HC + col] = o;
            else         *(ushort4*)&xr[(size_t)node*HC + (col-HC)] = o;
        }
    }
}

// ---------------- edge src/dst helper ----------------
__device__ __forceinline__ void edge_sd(int e, const int* __restrict__ edges, int* src, int* dst){
    if(e < EG){
        int b = e / E_, j = e - b*E_;
        *src = edges[(b*2+0)*E_ + j] + b*N_;
        *dst = edges[(b*2+1)*E_ + j] + b*N_;
    } else { *src = *dst = e - EG; }
}

// ---------------- K4: GATv2 edge logits + fused segment-max ----------------
__global__ __launch_bounds__(256) void k_logits(const unsigned short* __restrict__ xl,
        const unsigned short* __restrict__ xr, const int* __restrict__ edges,
        const float* __restrict__ atta, float* __restrict__ logits,
        unsigned* __restrict__ segmax){
    __shared__ float sA[HEADS*H_];
    int t = threadIdx.x;
    for(int i=t;i<HEADS*H_;i+=256) sA[i]=atta[i];
    __syncthreads();
    int lane = t & 63;
    int e = blockIdx.x*4 + (t >> 6);
    if(e >= ETOT) return;
    int src, dst; edge_sd(e, edges, &src, &dst);
    const unsigned short* xls = &xl[(size_t)src*HC];
    const unsigned short* xrd = &xr[(size_t)dst*HC];
    for(int hh=0; hh<HEADS; hh++){
        float s1 = bf2f(xls[hh*H_+lane])    + bf2f(xrd[hh*H_+lane]);
        float s2 = bf2f(xls[hh*H_+lane+64]) + bf2f(xrd[hh*H_+lane+64]);
        s1 = s1 > 0.f ? s1 : NEG_SLOPE*s1;
        s2 = s2 > 0.f ? s2 : NEG_SLOPE*s2;
        float p = s1*sA[hh*H_+lane] + s2*sA[hh*H_+lane+64];
        #pragma unroll
        for(int off=32; off; off>>=1) p += __shfl_xor(p, off);
        if(lane==0){
            logits[(size_t)e*HEADS+hh] = p;
            unsigned u = __float_as_uint(p);
            u = (u & 0x80000000u) ? ~u : (u | 0x80000000u);
            atomicMax(&segmax[dst*HEADS+hh], u);
        }
    }
}

// ---------------- K5b: p = exp(logit - m), segsum += p ----------------
__global__ void k_expsum(float* __restrict__ pbuf, const int* __restrict__ edges,
                         const unsigned* __restrict__ segmax, float* __restrict__ segsum){
    int idx = blockIdx.x*256 + threadIdx.x;
    if(idx >= ETOT*HEADS) return;
    int e = idx / HEADS, hh = idx - e*HEADS;
    int src, dst; edge_sd(e, edges, &src, &dst);
    unsigned u = segmax[dst*HEADS+hh];
    float m = (u & 0x80000000u) ? __uint_as_float(u ^ 0x80000000u) : __uint_as_float(~u);
    float p = __expf(pbuf[idx] - m);
    pbuf[idx] = p;
    atomicAdd(&segsum[dst*HEADS+hh], p);
}

// ---------------- K5c: alpha out + sparse node_out accumulation ----------------
__global__ void k_alpha(const float* __restrict__ pbuf, const float* __restrict__ segsum,
                        const int* __restrict__ edges, const unsigned short* __restrict__ xl,
                        float* __restrict__ out_alpha, float* __restrict__ node_out){
    int idx = blockIdx.x*256 + threadIdx.x;
    if(idx >= ETOT*HEADS) return;
    int e = idx / HEADS, hh = idx - e*HEADS;
    int src, dst; edge_sd(e, edges, &src, &dst);
    float a = pbuf[idx] / segsum[dst*HEADS+hh];
    out_alpha[idx] = a;
    if(dst % N_ == 0){   // only ego nodes b*N feed the head
        int b = dst / N_;
        const unsigned short* x = &xl[(size_t)src*HC + hh*H_];
        float* no = &node_out[b*HC + hh*H_];
        for(int c=0;c<H_;c++) atomicAdd(&no[c], a * bf2f(x[c]));
    }
}

// ---------------- K6: conv1 4->32, 32x32 -> 16x16, stride2 SAME ----------------
__global__ __launch_bounds__(256) void k_conv1(const float* __restrict__ im,
        const float* __restrict__ w, const float* __restrict__ bias, float* __restrict__ outp){
    __shared__ float sW[32*4*9];
    int t = threadIdx.x;
    for(int i=t;i<32*4*9;i+=256) sW[i]=w[i];
    __syncthreads();
    int idx = blockIdx.x*256 + t;
    if(idx >= 16*32*16*16) return;
    int ox = idx & 15, oy = (idx>>4)&15, oc = (idx>>8)&31, b = idx>>13;
    float acc = bias[oc];
    for(int ic=0;ic<4;ic++){
        const float* ip = &im[(size_t)((b*4+ic)*32)*32];
        const float* wp = &sW[(oc*4+ic)*9];
        #pragma unroll
        for(int ky=0;ky<3;ky++){
            int iy = oy*2+ky; if(iy>=32) continue;
            #pragma unroll
            for(int kx=0;kx<3;kx++){
                int ix = ox*2+kx; if(ix>=32) continue;
                acc = fmaf(ip[iy*32+ix], wp[ky*3+kx], acc);
            }
        }
    }
    outp[idx] = fmaxf(acc, 0.f);
}

// ---------------- K7: conv2 32->64, 16x16 -> 8x8 ----------------
__global__ __launch_bounds__(256) void k_conv2(const float* __restrict__ c1,
        const float* __restrict__ w, const float* __restrict__ bias, float* __restrict__ outp){
    int idx = blockIdx.x*256 + threadIdx.x;
    if(idx >= 16*64*8*8) return;
    int ox = idx & 7, oy = (idx>>3)&7, oc = (idx>>6)&63, b = idx>>12;
    float acc = bias[oc];
    for(int ic=0;ic<32;ic++){
        const float* ip = &c1[(size_t)((b*32+ic)*16)*16];
        const float* wp = &w[(oc*32+ic)*9];
        #pragma unroll
        for(int ky=0;ky<3;ky++){
            int iy = oy*2+ky; if(iy>=16) continue;
            #pragma unroll
            for(int kx=0;kx<3;kx++){
                int ix = ox*2+kx; if(ix>=16) continue;
                acc = fmaf(ip[iy*16+ix], wp[ky*3+kx], acc);
            }
        }
    }
    outp[idx] = fmaxf(acc, 0.f);
}

// ---------------- K8: temb partial GEMM, ILP-restructured ----------------
__global__ __launch_bounds__(256) void k_tembacc(const float* __restrict__ c2,
        const float* __restrict__ Wc, float* __restrict__ tacc){
    __shared__ float sC[128];
    int t = threadIdx.x;
    int b = blockIdx.x >> 5, ks = blockIdx.x & 31;
    int k0 = ks*128;
    if(t < 128) sC[t] = c2[(size_t)b*4096 + k0 + t];
    __syncthreads();
    int j = t & 127, sub = t >> 7;
    const float* wp = &Wc[(size_t)(k0 + sub*64)*H_ + j];
    const float* cp = &sC[sub*64];
    float a0=0.f, a1=0.f, a2=0.f, a3=0.f;
    #pragma unroll
    for(int kk=0; kk<64; kk+=4){
        a0 = fmaf(cp[kk+0], wp[(size_t)(kk+0)*H_], a0);
        a1 = fmaf(cp[kk+1], wp[(size_t)(kk+1)*H_], a1);
        a2 = fmaf(cp[kk+2], wp[(size_t)(kk+2)*H_], a2);
        a3 = fmaf(cp[kk+3], wp[(size_t)(kk+3)*H_], a3);
    }
    atomicAdd(&tacc[b*H_+j], (a0+a1)+(a2+a3));
}

// ---------------- K9: head ----------------
__global__ __launch_bounds__(256) void k_head(const float* __restrict__ node_out,
        const float* __restrict__ gat_bias, const float* __restrict__ tacc,
        const float* __restrict__ bc, const float* __restrict__ phase,
        const float* __restrict__ Wp, const float* __restrict__ bp,
        const float* __restrict__ Wh, const float* __restrict__ bh,
        const float* __restrict__ Wo, const float* __restrict__ bo,
        const float* __restrict__ Wa, const float* __restrict__ ba,
        float* __restrict__ out){
    __shared__ float sF[16][268];
    __shared__ float sHid[16][132];
    int t = threadIdx.x;
    for(int i=t;i<B_*H_;i+=256){
        int b=i>>7, c=i&127;
        float s=0.f;
        #pragma unroll
        for(int hh=0;hh<HEADS;hh++) s += node_out[b*HC + hh*H_ + c];
        sF[b][c] = s*(1.0f/HEADS) + gat_bias[c];
    }
    for(int i=t;i<B_*H_;i+=256){
        int b=i>>7, c=i&127;
        sF[b][128+c] = fmaxf(tacc[i] + bc[c], 0.f);
    }
    if(t < B_*P_){
        int b=t>>3, p=t&7;
        float s=bp[p];
        #pragma unroll
        for(int q=0;q<P_;q++) s = fmaf(phase[b*P_+q], Wp[q*P_+p], s);
        sF[b][256+p] = fmaxf(s, 0.f);
    }
    __syncthreads();
    for(int i=t;i<B_*H_;i+=256){
        int b=i>>7, j=i&127;
        float s=bh[j];
        for(int k=0;k<2*H_+P_;k++) s = fmaf(sF[b][k], Wh[k*H_+j], s);
        sHid[b][j]=fmaxf(s,0.f);
    }
    __syncthreads();
    if(t < B_*A_){
        int b=t>>3, a=t&7;
        float v=bo[0], ad=ba[a];
        for(int k=0;k<H_;k++){ float hv=sHid[b][k]; v = fmaf(hv,Wo[k],v); ad = fmaf(hv,Wa[k*A_+a],ad); }
        float m = ad;
        m += __shfl_xor(m,1); m += __shfl_xor(m,2); m += __shfl_xor(m,4);
        m *= 0.125f;
        out[b*A_+a] = v + ad - m;
    }
}

extern "C" void kernel_launch(void* const* d_in, const int* in_sizes, int n_in,
                              void* d_out, int out_size, void* d_ws, size_t ws_size,
                              hipStream_t stream) {
    (void)in_sizes; (void)n_in; (void)out_size; (void)ws_size;
    const float* obs      = (const float*)d_in[0];
    const float* phase    = (const float*)d_in[1];
    const float* obs_map  = (const float*)d_in[2];
    const int*   edges    = (const int*)  d_in[3];
    const float* W_nbrs   = (const float*)d_in[5];
    const float* b_nbrs   = (const float*)d_in[6];
    const float* W_ih     = (const float*)d_in[7];
    const float* W_hh     = (const float*)d_in[8];
    const float* b_ih     = (const float*)d_in[9];
    const float* b_hh     = (const float*)d_in[10];
    const float* Wl       = (const float*)d_in[11];
    const float* Wr       = (const float*)d_in[12];
    const float* att_a    = (const float*)d_in[13];
    const float* gat_bias = (const float*)d_in[14];
    const float* conv1_w  = (const float*)d_in[15];
    const float* conv1_b  = (const float*)d_in[16];
    const float* conv2_w  = (const float*)d_in[17];
    const float* conv2_b  = (const float*)d_in[18];
    const float* Wc       = (const float*)d_in[19];
    const float* bc       = (const float*)d_in[20];
    const float* Wp       = (const float*)d_in[21];
    const float* bp       = (const float*)d_in[22];
    const float* Wh       = (const float*)d_in[23];
    const float* bh       = (const float*)d_in[24];
    const float* Wo       = (const float*)d_in[25];
    const float* bo       = (const float*)d_in[26];
    const float* Wa       = (const float*)d_in[27];
    const float* ba       = (const float*)d_in[28];

    float* out = (float*)d_out;                 // [0,128): out ; [128,400128): alpha
    float* w   = (float*)d_ws;

    // ws layout (float units)
    size_t off = 0;
    unsigned short* hbuf = (unsigned short*)(w + off); off += (size_t)BN_*H_/2;
    unsigned short* xl   = (unsigned short*)(w + off); off += (size_t)BN_*HC/2;
    unsigned short* xr   = (unsigned short*)(w + off); off += (size_t)BN_*HC/2;
    float* pbuf   = w + off; off += (size_t)ETOT*HEADS;
    unsigned* segmax = (unsigned*)(w + off); off += (size_t)BN_*HEADS;
    float* segsum = w + off; off += (size_t)BN_*HEADS;
    float* nodeo  = w + off; off += (size_t)B_*HC;
    float* c1     = w + off; off += (size_t)16*32*16*16;
    float* c2     = w + off; off += (size_t)16*64*8*8;
    float* tacc   = w + off; off += (size_t)B_*H_;
    unsigned short* Wihb = (unsigned short*)(w + off); off += (size_t)H_*G3/2;
    unsigned short* Whhb = (unsigned short*)(w + off); off += (size_t)H_*G3/2;
    unsigned short* WTb  = (unsigned short*)(w + off); off += (size_t)2*HC*H_/2;
    unsigned short* WnTb = (unsigned short*)(w + off); off += (size_t)H_*32/2;

    k_prep<<<(2*HC*H_+255)/256, 256, 0, stream>>>(W_ih, W_hh, Wl, Wr, W_nbrs,
                                                  Wihb, Whhb, WTb, WnTb);
    k_init<<<(BN_*HEADS+255)/256, 256, 0, stream>>>(segmax, segsum, nodeo, tacc);

    k_gruf<<<BN_/16, 512, 0, stream>>>(obs, WnTb, b_nbrs, Wihb, b_ih, Whhb, b_hh, hbuf);

    k_xlxr<<<dim3(BN_/64, 5), 256, 0, stream>>>(hbuf, WTb, xl, xr);
    k_logits<<<ETOT/4, 256, 0, stream>>>(xl, xr, edges, att_a, pbuf, segmax);
    k_expsum<<<(ETOT*HEADS+255)/256, 256, 0, stream>>>(pbuf, edges, segmax, segsum);
    k_alpha <<<(ETOT*HEADS+255)/256, 256, 0, stream>>>(pbuf, segsum, edges, xl, out+128, nodeo);
    k_conv1<<<(16*32*16*16)/256, 256, 0, stream>>>(obs_map, conv1_w, conv1_b, c1);
    k_conv2<<<(16*64*8*8)/256, 256, 0, stream>>>(c1, conv2_w, conv2_b, c2);
    k_tembacc<<<16*32, 256, 0, stream>>>(c2, Wc, tacc);
    k_head<<<1, 256, 0, stream>>>(nodeo, gat_bias, tacc, bc, phase,
                                  Wp, bp, Wh, bh, Wo, bo, Wa, ba, out);
}

// Round 6
// 258.465 us; speedup vs baseline: 6.0862x; 1.1686x over previous
//
#include <hip/hip_runtime.h>
#include <hip/hip_bf16.h>
#include <math.h>

#define B_    16
#define N_    1000
#define BN_   16000
#define T_    16
#define FO    16
#define H_    128
#define G3    384       // 3*H
#define HEADS 5
#define HC    640       // heads*H
#define E_    4000
#define EG    64000     // B*E
#define ETOT  80000     // EG + BN self loops
#define P_    8
#define A_    8
#define NEG_SLOPE 0.2f

typedef __attribute__((ext_vector_type(8))) short bf16x8;
typedef __attribute__((ext_vector_type(4))) float f32x4;

__device__ __forceinline__ float bf2f(unsigned short u){ return __uint_as_float(((unsigned)u)<<16); }
__device__ __forceinline__ unsigned short f2bf(float x){
    unsigned u = __float_as_uint(x);
    unsigned r = (u + 0x7FFFu + ((u>>16)&1u)) >> 16;
    return (unsigned short)r;
}
__device__ __forceinline__ unsigned cvtpk(float lo, float hi){
    unsigned r;
    asm volatile("v_cvt_pk_bf16_f32 %0, %1, %2" : "=v"(r) : "v"(lo), "v"(hi));
    return r;
}
__device__ __forceinline__ float rcpf(float x){ return __builtin_amdgcn_rcpf(x); }

// ---------------- K_prep: bf16 weight prep ----------------
__global__ void k_prep(const float* __restrict__ Wih, const float* __restrict__ Whh,
                       const float* __restrict__ Wl, const float* __restrict__ Wr,
                       const float* __restrict__ Wn,
                       unsigned short* __restrict__ Wihb, unsigned short* __restrict__ Whhb,
                       unsigned short* __restrict__ WTb, unsigned short* __restrict__ WnTb){
    int i = blockIdx.x*256 + threadIdx.x;
    if(i < G3*H_){ Wihb[i] = f2bf(Wih[i]); Whhb[i] = f2bf(Whh[i]); }
    if(i < 2*HC*H_){
        int c = i >> 7, k = i & 127;
        float v = (c < HC) ? Wl[(size_t)k*HC + c] : Wr[(size_t)k*HC + (c-HC)];
        WTb[i] = f2bf(v);
    }
    if(i < H_*32){
        int c = i >> 5, k = i & 31;
        WnTb[i] = (k < FO) ? f2bf(Wn[k*H_ + c]) : (unsigned short)0;
    }
}

// ---------------- K_init ----------------
__global__ void k_init(unsigned* __restrict__ segmax, float* __restrict__ segsum,
                       float* __restrict__ node_out, float* __restrict__ tacc){
    int i = blockIdx.x*256 + threadIdx.x;
    if(i < BN_*HEADS){ segmax[i] = 0x007FFFFFu; segsum[i] = 0.0f; }
    if(i < B_*HC)  node_out[i] = 0.0f;
    if(i < B_*H_)  tacc[i] = 0.0f;
}

// ============ K_GRUF v2: fused obs-MLP + gx + GRU, 32 nodes/block ============
// 8 waves, 2 node-groups per wave. ONE barrier per step: X(s+1) is computed at the
// END of step s (obs prefetched global->reg at step START, latency hidden under
// the gate phase), double-buffered sX/sH. rcp + cvt_pk replace div + scalar f2bf.
__global__ __launch_bounds__(512,2) void k_gruf(const float* __restrict__ obs,
        const unsigned short* __restrict__ WnTb, const float* __restrict__ bn,
        const unsigned short* __restrict__ Wihb, const float* __restrict__ bih,
        const unsigned short* __restrict__ Whhb, const float* __restrict__ bhh,
        unsigned short* __restrict__ hout){
    __shared__ unsigned short sX[2*4096];   // [buf][grp(2)][16 nodes][128], swizzled
    __shared__ unsigned short sH[2*4096];
    int t = threadIdx.x;
    int w = t>>6, lane = t&63, lq = lane>>4, lm = lane&15;

    // persistent weight fragments (wave w owns gate tiles r=w, z=8+w, n=16+w)
    bf16x8 wfi[3][4], wfh[3][4];
    #pragma unroll
    for(int i=0;i<3;i++){
        int row = (8*i + w)*16 + lm;
        #pragma unroll
        for(int kt=0;kt<4;kt++){
            wfi[i][kt] = *(const bf16x8*)&Wihb[row*H_ + kt*32 + lq*8];
            wfh[i][kt] = *(const bf16x8*)&Whhb[row*H_ + kt*32 + lq*8];
        }
    }
    bf16x8 wfn = *(const bf16x8*)&WnTb[(w*16+lm)*32 + lq*8];
    int cb = w*16 + lq*4;
    f32x4 bnv = *(const f32x4*)&bn[cb];
    f32x4 b_r, b_z, bxn, bhn;
    { f32x4 t1=*(const f32x4*)&bih[cb],     t2=*(const f32x4*)&bhh[cb];     b_r=t1+t2; }
    { f32x4 t1=*(const f32x4*)&bih[128+cb], t2=*(const f32x4*)&bhh[128+cb]; b_z=t1+t2; }
    bxn = *(const f32x4*)&bih[256+cb];
    bhn = *(const f32x4*)&bhh[256+cb];

    // LDS addresses (ushort units)
    int rd[4];
    #pragma unroll
    for(int kt=0;kt<4;kt++) rd[kt] = lm*128 + (((4*kt+lq)^(lm&7))<<3);
    const int wrt = lm*128 + (((2*w + (lq>>1))^(lm&7))<<3) + ((lq&1)<<2);

    int nodeBase = blockIdx.x*32;
    const float* obp0 = &obs[(size_t)(nodeBase + lm)*256 + lq*8];
    const float* obp1 = obp0 + 16*256;

    for(int i=t;i<2048;i+=512) ((unsigned*)sH)[i] = 0u;   // zero sH buf 0
    float ho[2][4] = {{0.f,0.f,0.f,0.f},{0.f,0.f,0.f,0.f}};

    // prologue: X(0)
    float4 oA[2], oB[2];
    if(lq < 2){
        oA[0] = *(const float4*)(obp0);     oB[0] = *(const float4*)(obp0+4);
        oA[1] = *(const float4*)(obp1);     oB[1] = *(const float4*)(obp1+4);
    }
    #pragma unroll
    for(int g=0; g<2; g++){
        bf16x8 ob = (bf16x8){0,0,0,0,0,0,0,0};
        if(lq < 2){
            union { uint4 u; bf16x8 v; } cv;
            cv.u = make_uint4(cvtpk(oA[g].x,oA[g].y), cvtpk(oA[g].z,oA[g].w),
                              cvtpk(oB[g].x,oB[g].y), cvtpk(oB[g].z,oB[g].w));
            ob = cv.v;
        }
        f32x4 xa = (f32x4){0.f,0.f,0.f,0.f};
        xa = __builtin_amdgcn_mfma_f32_16x16x32_bf16(wfn, ob, xa, 0,0,0);
        unsigned u0 = cvtpk(fmaxf(xa[0]+bnv[0],0.f), fmaxf(xa[1]+bnv[1],0.f));
        unsigned u1 = cvtpk(fmaxf(xa[2]+bnv[2],0.f), fmaxf(xa[3]+bnv[3],0.f));
        *(uint2*)&sX[g*2048 + wrt] = make_uint2(u0,u1);
    }
    __syncthreads();

    int p = 0;
    #pragma unroll 1
    for(int s=0; s<T_; s++){
        // issue next-step obs loads early (latency hides under gate phase)
        if(s < T_-1 && lq < 2){
            const float* q0 = obp0 + (s+1)*16;
            const float* q1 = obp1 + (s+1)*16;
            oA[0] = *(const float4*)(q0);   oB[0] = *(const float4*)(q0+4);
            oA[1] = *(const float4*)(q1);   oB[1] = *(const float4*)(q1+4);
        }
        // gate phase, 2 node groups
        #pragma unroll
        for(int g=0; g<2; g++){
            int base = p*4096 + g*2048;
            bf16x8 xb[4], hb[4];
            #pragma unroll
            for(int kt=0;kt<4;kt++){
                xb[kt] = *(const bf16x8*)&sX[base + rd[kt]];
                hb[kt] = *(const bf16x8*)&sH[base + rd[kt]];
            }
            f32x4 ari={0,0,0,0}, azi={0,0,0,0}, axi={0,0,0,0};
            f32x4 arh={0,0,0,0}, azh={0,0,0,0}, ahh={0,0,0,0};
            #pragma unroll
            for(int kt=0;kt<4;kt++){
                ari = __builtin_amdgcn_mfma_f32_16x16x32_bf16(wfi[0][kt], xb[kt], ari, 0,0,0);
                azi = __builtin_amdgcn_mfma_f32_16x16x32_bf16(wfi[1][kt], xb[kt], azi, 0,0,0);
                axi = __builtin_amdgcn_mfma_f32_16x16x32_bf16(wfi[2][kt], xb[kt], axi, 0,0,0);
                arh = __builtin_amdgcn_mfma_f32_16x16x32_bf16(wfh[0][kt], hb[kt], arh, 0,0,0);
                azh = __builtin_amdgcn_mfma_f32_16x16x32_bf16(wfh[1][kt], hb[kt], azh, 0,0,0);
                ahh = __builtin_amdgcn_mfma_f32_16x16x32_bf16(wfh[2][kt], hb[kt], ahh, 0,0,0);
            }
            #pragma unroll
            for(int v=0;v<4;v++){
                float er = __expf(-(ari[v] + arh[v] + b_r[v]));
                float r  = rcpf(1.f + er);
                float ez = __expf(-(azi[v] + azh[v] + b_z[v]));
                float z  = rcpf(1.f + ez);
                float xn = axi[v] + bxn[v] + r*(ahh[v] + bhn[v]);
                float en = __expf(-2.f*xn);
                float nn = 2.f*rcpf(1.f + en) - 1.f;
                ho[g][v] = nn + z*(ho[g][v] - nn);
            }
            unsigned u0 = cvtpk(ho[g][0], ho[g][1]);
            unsigned u1 = cvtpk(ho[g][2], ho[g][3]);
            *(uint2*)&sH[(p^1)*4096 + g*2048 + wrt] = make_uint2(u0,u1);
        }
        // X(s+1) pipeline
        if(s < T_-1){
            #pragma unroll
            for(int g=0; g<2; g++){
                bf16x8 ob = (bf16x8){0,0,0,0,0,0,0,0};
                if(lq < 2){
                    union { uint4 u; bf16x8 v; } cv;
                    cv.u = make_uint4(cvtpk(oA[g].x,oA[g].y), cvtpk(oA[g].z,oA[g].w),
                                      cvtpk(oB[g].x,oB[g].y), cvtpk(oB[g].z,oB[g].w));
                    ob = cv.v;
                }
                f32x4 xa = (f32x4){0.f,0.f,0.f,0.f};
                xa = __builtin_amdgcn_mfma_f32_16x16x32_bf16(wfn, ob, xa, 0,0,0);
                unsigned u0 = cvtpk(fmaxf(xa[0]+bnv[0],0.f), fmaxf(xa[1]+bnv[1],0.f));
                unsigned u1 = cvtpk(fmaxf(xa[2]+bnv[2],0.f), fmaxf(xa[3]+bnv[3],0.f));
                *(uint2*)&sX[(p^1)*4096 + g*2048 + wrt] = make_uint2(u0,u1);
            }
        }
        __syncthreads();
        p ^= 1;
    }
    #pragma unroll
    for(int g=0; g<2; g++){
        unsigned u0 = cvtpk(ho[g][0], ho[g][1]);
        unsigned u1 = cvtpk(ho[g][2], ho[g][3]);
        *(uint2*)&hout[(size_t)(nodeBase + g*16 + lm)*H_ + cb] = make_uint2(u0,u1);
    }
}

// ============ K3: xl|xr = h @ [Wl|Wr], MFMA bf16, no LDS ============
__global__ __launch_bounds__(256) void k_xlxr(const unsigned short* __restrict__ hb16,
        const unsigned short* __restrict__ WTb,
        unsigned short* __restrict__ xl, unsigned short* __restrict__ xr){
    int t = threadIdx.x;
    int w = t>>6, lane = t&63, lq = lane>>4, lm = lane&15;
    int nblk = blockIdx.x*64;
    int ct0 = blockIdx.y*16 + w*4;

    bf16x8 wf[4][4];
    #pragma unroll
    for(int i=0;i<4;i++){
        int row = (ct0+i)*16 + lm;
        #pragma unroll
        for(int kt=0;kt<4;kt++)
            wf[i][kt] = *(const bf16x8*)&WTb[(size_t)row*H_ + kt*32 + lq*8];
    }
    for(int g=0; g<4; g++){
        int node = nblk + g*16 + lm;
        bf16x8 hb[4];
        #pragma unroll
        for(int kt=0;kt<4;kt++)
            hb[kt] = *(const bf16x8*)&hb16[(size_t)node*H_ + kt*32 + lq*8];
        f32x4 acc[4];
        #pragma unroll
        for(int i=0;i<4;i++) acc[i] = (f32x4){0.f,0.f,0.f,0.f};
        #pragma unroll
        for(int kt=0;kt<4;kt++){
            #pragma unroll
            for(int i=0;i<4;i++)
                acc[i] = __builtin_amdgcn_mfma_f32_16x16x32_bf16(wf[i][kt], hb[kt], acc[i], 0,0,0);
        }
        #pragma unroll
        for(int i=0;i<4;i++){
            int col = (ct0+i)*16 + lq*4;
            ushort4 o;
            o.x=f2bf(acc[i][0]); o.y=f2bf(acc[i][1]); o.z=f2bf(acc[i][2]); o.w=f2bf(acc[i][3]);
            if(col < HC) *(ushort4*)&xl[(size_t)node*HC + col] = o;
            else         *(ushort4*)&xr[(size_t)node*HC + (col-HC)] = o;
        }
    }
}

// ---------------- edge src/dst helper ----------------
__device__ __forceinline__ void edge_sd(int e, const int* __restrict__ edges, int* src, int* dst){
    if(e < EG){
        int b = e / E_, j = e - b*E_;
        *src = edges[(b*2+0)*E_ + j] + b*N_;
        *dst = edges[(b*2+1)*E_ + j] + b*N_;
    } else { *src = *dst = e - EG; }
}

// ---------------- K4: GATv2 edge logits + fused segment-max ----------------
__global__ __launch_bounds__(256) void k_logits(const unsigned short* __restrict__ xl,
        const unsigned short* __restrict__ xr, const int* __restrict__ edges,
        const float* __restrict__ atta, float* __restrict__ logits,
        unsigned* __restrict__ segmax){
    __shared__ float sA[HEADS*H_];
    int t = threadIdx.x;
    for(int i=t;i<HEADS*H_;i+=256) sA[i]=atta[i];
    __syncthreads();
    int lane = t & 63;
    int e = blockIdx.x*4 + (t >> 6);
    if(e >= ETOT) return;
    int src, dst; edge_sd(e, edges, &src, &dst);
    const unsigned short* xls = &xl[(size_t)src*HC];
    const unsigned short* xrd = &xr[(size_t)dst*HC];
    for(int hh=0; hh<HEADS; hh++){
        float s1 = bf2f(xls[hh*H_+lane])    + bf2f(xrd[hh*H_+lane]);
        float s2 = bf2f(xls[hh*H_+lane+64]) + bf2f(xrd[hh*H_+lane+64]);
        s1 = s1 > 0.f ? s1 : NEG_SLOPE*s1;
        s2 = s2 > 0.f ? s2 : NEG_SLOPE*s2;
        float p = s1*sA[hh*H_+lane] + s2*sA[hh*H_+lane+64];
        #pragma unroll
        for(int off=32; off; off>>=1) p += __shfl_xor(p, off);
        if(lane==0){
            logits[(size_t)e*HEADS+hh] = p;
            unsigned u = __float_as_uint(p);
            u = (u & 0x80000000u) ? ~u : (u | 0x80000000u);
            atomicMax(&segmax[dst*HEADS+hh], u);
        }
    }
}

// ---------------- K5b: p = exp(logit - m), segsum += p ----------------
__global__ void k_expsum(float* __restrict__ pbuf, const int* __restrict__ edges,
                         const unsigned* __restrict__ segmax, float* __restrict__ segsum){
    int idx = blockIdx.x*256 + threadIdx.x;
    if(idx >= ETOT*HEADS) return;
    int e = idx / HEADS, hh = idx - e*HEADS;
    int src, dst; edge_sd(e, edges, &src, &dst);
    unsigned u = segmax[dst*HEADS+hh];
    float m = (u & 0x80000000u) ? __uint_as_float(u ^ 0x80000000u) : __uint_as_float(~u);
    float p = __expf(pbuf[idx] - m);
    pbuf[idx] = p;
    atomicAdd(&segsum[dst*HEADS+hh], p);
}

// ---------------- K5c: alpha out + sparse node_out accumulation ----------------
__global__ void k_alpha(const float* __restrict__ pbuf, const float* __restrict__ segsum,
                        const int* __restrict__ edges, const unsigned short* __restrict__ xl,
                        float* __restrict__ out_alpha, float* __restrict__ node_out){
    int idx = blockIdx.x*256 + threadIdx.x;
    if(idx >= ETOT*HEADS) return;
    int e = idx / HEADS, hh = idx - e*HEADS;
    int src, dst; edge_sd(e, edges, &src, &dst);
    float a = pbuf[idx] / segsum[dst*HEADS+hh];
    out_alpha[idx] = a;
    if(dst % N_ == 0){
        int b = dst / N_;
        const unsigned short* x = &xl[(size_t)src*HC + hh*H_];
        float* no = &node_out[b*HC + hh*H_];
        for(int c=0;c<H_;c++) atomicAdd(&no[c], a * bf2f(x[c]));
    }
}

// ---------------- K6: conv1 ----------------
__global__ __launch_bounds__(256) void k_conv1(const float* __restrict__ im,
        const float* __restrict__ w, const float* __restrict__ bias, float* __restrict__ outp){
    __shared__ float sW[32*4*9];
    int t = threadIdx.x;
    for(int i=t;i<32*4*9;i+=256) sW[i]=w[i];
    __syncthreads();
    int idx = blockIdx.x*256 + t;
    if(idx >= 16*32*16*16) return;
    int ox = idx & 15, oy = (idx>>4)&15, oc = (idx>>8)&31, b = idx>>13;
    float acc = bias[oc];
    for(int ic=0;ic<4;ic++){
        const float* ip = &im[(size_t)((b*4+ic)*32)*32];
        const float* wp = &sW[(oc*4+ic)*9];
        #pragma unroll
        for(int ky=0;ky<3;ky++){
            int iy = oy*2+ky; if(iy>=32) continue;
            #pragma unroll
            for(int kx=0;kx<3;kx++){
                int ix = ox*2+kx; if(ix>=32) continue;
                acc = fmaf(ip[iy*32+ix], wp[ky*3+kx], acc);
            }
        }
    }
    outp[idx] = fmaxf(acc, 0.f);
}

// ---------------- K7: conv2 ----------------
__global__ __launch_bounds__(256) void k_conv2(const float* __restrict__ c1,
        const float* __restrict__ w, const float* __restrict__ bias, float* __restrict__ outp){
    int idx = blockIdx.x*256 + threadIdx.x;
    if(idx >= 16*64*8*8) return;
    int ox = idx & 7, oy = (idx>>3)&7, oc = (idx>>6)&63, b = idx>>12;
    float acc = bias[oc];
    for(int ic=0;ic<32;ic++){
        const float* ip = &c1[(size_t)((b*32+ic)*16)*16];
        const float* wp = &w[(oc*32+ic)*9];
        #pragma unroll
        for(int ky=0;ky<3;ky++){
            int iy = oy*2+ky; if(iy>=16) continue;
            #pragma unroll
            for(int kx=0;kx<3;kx++){
                int ix = ox*2+kx; if(ix>=16) continue;
                acc = fmaf(ip[iy*16+ix], wp[ky*3+kx], acc);
            }
        }
    }
    outp[idx] = fmaxf(acc, 0.f);
}

// ---------------- K8: temb partial GEMM ----------------
__global__ __launch_bounds__(256) void k_tembacc(const float* __restrict__ c2,
        const float* __restrict__ Wc, float* __restrict__ tacc){
    __shared__ float sC[128];
    int t = threadIdx.x;
    int b = blockIdx.x >> 5, ks = blockIdx.x & 31;
    int k0 = ks*128;
    if(t < 128) sC[t] = c2[(size_t)b*4096 + k0 + t];
    __syncthreads();
    int j = t & 127, sub = t >> 7;
    const float* wp = &Wc[(size_t)(k0 + sub*64)*H_ + j];
    const float* cp = &sC[sub*64];
    float a0=0.f, a1=0.f, a2=0.f, a3=0.f;
    #pragma unroll
    for(int kk=0; kk<64; kk+=4){
        a0 = fmaf(cp[kk+0], wp[(size_t)(kk+0)*H_], a0);
        a1 = fmaf(cp[kk+1], wp[(size_t)(kk+1)*H_], a1);
        a2 = fmaf(cp[kk+2], wp[(size_t)(kk+2)*H_], a2);
        a3 = fmaf(cp[kk+3], wp[(size_t)(kk+3)*H_], a3);
    }
    atomicAdd(&tacc[b*H_+j], (a0+a1)+(a2+a3));
}

// ---------------- K9: head ----------------
__global__ __launch_bounds__(256) void k_head(const float* __restrict__ node_out,
        const float* __restrict__ gat_bias, const float* __restrict__ tacc,
        const float* __restrict__ bc, const float* __restrict__ phase,
        const float* __restrict__ Wp, const float* __restrict__ bp,
        const float* __restrict__ Wh, const float* __restrict__ bh,
        const float* __restrict__ Wo, const float* __restrict__ bo,
        const float* __restrict__ Wa, const float* __restrict__ ba,
        float* __restrict__ out){
    __shared__ float sF[16][268];
    __shared__ float sHid[16][132];
    int t = threadIdx.x;
    for(int i=t;i<B_*H_;i+=256){
        int b=i>>7, c=i&127;
        float s=0.f;
        #pragma unroll
        for(int hh=0;hh<HEADS;hh++) s += node_out[b*HC + hh*H_ + c];
        sF[b][c] = s*(1.0f/HEADS) + gat_bias[c];
    }
    for(int i=t;i<B_*H_;i+=256){
        int b=i>>7, c=i&127;
        sF[b][128+c] = fmaxf(tacc[i] + bc[c], 0.f);
    }
    if(t < B_*P_){
        int b=t>>3, p=t&7;
        float s=bp[p];
        #pragma unroll
        for(int q=0;q<P_;q++) s = fmaf(phase[b*P_+q], Wp[q*P_+p], s);
        sF[b][256+p] = fmaxf(s, 0.f);
    }
    __syncthreads();
    for(int i=t;i<B_*H_;i+=256){
        int b=i>>7, j=i&127;
        float s=bh[j];
        for(int k=0;k<2*H_+P_;k++) s = fmaf(sF[b][k], Wh[k*H_+j], s);
        sHid[b][j]=fmaxf(s,0.f);
    }
    __syncthreads();
    if(t < B_*A_){
        int b=t>>3, a=t&7;
        float v=bo[0], ad=ba[a];
        for(int k=0;k<H_;k++){ float hv=sHid[b][k]; v = fmaf(hv,Wo[k],v); ad = fmaf(hv,Wa[k*A_+a],ad); }
        float m = ad;
        m += __shfl_xor(m,1); m += __shfl_xor(m,2); m += __shfl_xor(m,4);
        m *= 0.125f;
        out[b*A_+a] = v + ad - m;
    }
}

extern "C" void kernel_launch(void* const* d_in, const int* in_sizes, int n_in,
                              void* d_out, int out_size, void* d_ws, size_t ws_size,
                              hipStream_t stream) {
    (void)in_sizes; (void)n_in; (void)out_size; (void)ws_size;
    const float* obs      = (const float*)d_in[0];
    const float* phase    = (const float*)d_in[1];
    const float* obs_map  = (const float*)d_in[2];
    const int*   edges    = (const int*)  d_in[3];
    const float* W_nbrs   = (const float*)d_in[5];
    const float* b_nbrs   = (const float*)d_in[6];
    const float* W_ih     = (const float*)d_in[7];
    const float* W_hh     = (const float*)d_in[8];
    const float* b_ih     = (const float*)d_in[9];
    const float* b_hh     = (const float*)d_in[10];
    const float* Wl       = (const float*)d_in[11];
    const float* Wr       = (const float*)d_in[12];
    const float* att_a    = (const float*)d_in[13];
    const float* gat_bias = (const float*)d_in[14];
    const float* conv1_w  = (const float*)d_in[15];
    const float* conv1_b  = (const float*)d_in[16];
    const float* conv2_w  = (const float*)d_in[17];
    const float* conv2_b  = (const float*)d_in[18];
    const float* Wc       = (const float*)d_in[19];
    const float* bc       = (const float*)d_in[20];
    const float* Wp       = (const float*)d_in[21];
    const float* bp       = (const float*)d_in[22];
    const float* Wh       = (const float*)d_in[23];
    const float* bh       = (const float*)d_in[24];
    const float* Wo       = (const float*)d_in[25];
    const float* bo       = (const float*)d_in[26];
    const float* Wa       = (const float*)d_in[27];
    const float* ba       = (const float*)d_in[28];

    float* out = (float*)d_out;                 // [0,128): out ; [128,400128): alpha
    float* w   = (float*)d_ws;

    size_t off = 0;
    unsigned short* hbuf = (unsigned short*)(w + off); off += (size_t)BN_*H_/2;
    unsigned short* xl   = (unsigned short*)(w + off); off += (size_t)BN_*HC/2;
    unsigned short* xr   = (unsigned short*)(w + off); off += (size_t)BN_*HC/2;
    float* pbuf   = w + off; off += (size_t)ETOT*HEADS;
    unsigned* segmax = (unsigned*)(w + off); off += (size_t)BN_*HEADS;
    float* segsum = w + off; off += (size_t)BN_*HEADS;
    float* nodeo  = w + off; off += (size_t)B_*HC;
    float* c1     = w + off; off += (size_t)16*32*16*16;
    float* c2     = w + off; off += (size_t)16*64*8*8;
    float* tacc   = w + off; off += (size_t)B_*H_;
    unsigned short* Wihb = (unsigned short*)(w + off); off += (size_t)H_*G3/2;
    unsigned short* Whhb = (unsigned short*)(w + off); off += (size_t)H_*G3/2;
    unsigned short* WTb  = (unsigned short*)(w + off); off += (size_t)2*HC*H_/2;
    unsigned short* WnTb = (unsigned short*)(w + off); off += (size_t)H_*32/2;

    k_prep<<<(2*HC*H_+255)/256, 256, 0, stream>>>(W_ih, W_hh, Wl, Wr, W_nbrs,
                                                  Wihb, Whhb, WTb, WnTb);
    k_init<<<(BN_*HEADS+255)/256, 256, 0, stream>>>(segmax, segsum, nodeo, tacc);

    k_gruf<<<BN_/32, 512, 0, stream>>>(obs, WnTb, b_nbrs, Wihb, b_ih, Whhb, b_hh, hbuf);

    k_xlxr<<<dim3(BN_/64, 5), 256, 0, stream>>>(hbuf, WTb, xl, xr);
    k_logits<<<ETOT/4, 256, 0, stream>>>(xl, xr, edges, att_a, pbuf, segmax);
    k_expsum<<<(ETOT*HEADS+255)/256, 256, 0, stream>>>(pbuf, edges, segmax, segsum);
    k_alpha <<<(ETOT*HEADS+255)/256, 256, 0, stream>>>(pbuf, segsum, edges, xl, out+128, nodeo);
    k_conv1<<<(16*32*16*16)/256, 256, 0, stream>>>(obs_map, conv1_w, conv1_b, c1);
    k_conv2<<<(16*64*8*8)/256, 256, 0, stream>>>(c1, conv2_w, conv2_b, c2);
    k_tembacc<<<16*32, 256, 0, stream>>>(c2, Wc, tacc);
    k_head<<<1, 256, 0, stream>>>(nodeo, gat_bias, tacc, bc, phase,
                                  Wp, bp, Wh, bh, Wo, bo, Wa, ba, out);
}